// Round 8
// baseline (4428.775 us; speedup 1.0000x reference)
//
#include <hip/hip_runtime.h>
#include <math.h>

#define BSZ 1024
#define SLEN 32
#define TLEN 32
#define EDIM 128
#define HLD 264    // u16 row stride for bf16 h in LDS
#define HFLD 260   // f32 row stride
#define CTXLD 520  // u16 row stride for ctx
#define HWLD 260   // f32 row stride for hWd

typedef unsigned short u16;
typedef __attribute__((ext_vector_type(8))) short bf16x8;
typedef __attribute__((ext_vector_type(4))) float f32x4;

__device__ __forceinline__ float sgm(float x) { return 1.0f / (1.0f + __expf(-x)); }
__device__ __forceinline__ float tanh_fast(float x) {
  float e = __expf(-2.0f * fabsf(x));
  float t = (1.0f - e) / (1.0f + e);
  return copysignf(t, x);
}
__device__ __forceinline__ u16 f2b(float f) {
  union { float f; unsigned u; } v; v.f = f;
  unsigned r = v.u + 0x7fffu + ((v.u >> 16) & 1u);
  return (u16)(r >> 16);
}
__device__ __forceinline__ float b2f(u16 h) {
  union { unsigned u; float f; } v; v.u = ((unsigned)h) << 16; return v.f;
}

typedef __attribute__((address_space(1))) const void gv_t;
typedef __attribute__((address_space(3))) void lv_t;
__device__ __forceinline__ void gload16(const void* g, void* l) {
  __builtin_amdgcn_global_load_lds((gv_t*)g, (lv_t*)l, 16, 0, 0);
}

// ---------------- gi tables -------------------------------------------------------
__global__ __launch_bounds__(256) void k_gi_table(const float* __restrict__ emb,
                                                  const float* __restrict__ Wih, int ldw,
                                                  const float* __restrict__ bih,
                                                  float* __restrict__ tab) {
  int v = blockIdx.x;
  int g = blockIdx.y * 256 + threadIdx.x;
  __shared__ float e[EDIM];
  if (threadIdx.x < EDIM) e[threadIdx.x] = emb[v * EDIM + threadIdx.x];
  __syncthreads();
  const float4* w4 = (const float4*)(Wih + (size_t)g * ldw);
  float acc = 0.f;
#pragma unroll
  for (int j = 0; j < EDIM / 4; ++j) {
    float4 w = w4[j];
    acc += w.x * e[4 * j] + w.y * e[4 * j + 1] + w.z * e[4 * j + 2] + w.w * e[4 * j + 3];
  }
  tab[(size_t)v * 768 + g] = acc + bih[g];
}

// ---------------- fp32 -> bf16 weight pack ---------------------------------------
__global__ __launch_bounds__(256) void k_pack(u16* __restrict__ dst,
                                              const float* __restrict__ src, int ld,
                                              int off, int n) {
  int r = blockIdx.x;
  for (int c = threadIdx.x; c < n; c += 256)
    dst[(size_t)r * n + c] = f2b(src[(size_t)r * ld + off + c]);
}

// gates B matrix (1024 x 768)
__global__ __launch_bounds__(256) void k_pack_gates(u16* __restrict__ Wg,
                                                    const float* __restrict__ dWih,
                                                    const float* __restrict__ dWhh) {
  int r = blockIdx.x;
  for (int c = threadIdx.x; c < 768; c += 256) {
    float v;
    if (r < 512)      v = (c < 512) ? dWih[(size_t)r * 640 + 128 + c] : dWhh[(size_t)r * 256 + (c - 512)];
    else if (r < 768) v = (c < 512) ? dWih[(size_t)r * 640 + 128 + c] : 0.f;
    else              v = (c < 512) ? 0.f : dWhh[(size_t)(r - 256) * 256 + (c - 512)];
    Wg[(size_t)r * 768 + c] = f2b(v);
  }
}

// ---------------- bf16 MFMA GEMM 128x64: out = A.B^T + bias ----------------------
template <bool B16OUT>
__global__ __launch_bounds__(256) void k_bgemm(const u16* __restrict__ A, int lda,
                                               const u16* __restrict__ B, int ldb,
                                               const float* __restrict__ bias,
                                               void* __restrict__ outv, int ldo, int K) {
  __shared__ u16 sA[128 * 64];
  __shared__ u16 sB[64 * 64];
  int m0 = blockIdx.x * 128, n0 = blockIdx.y * 64;
  int tid = threadIdx.x, w = tid >> 6, l = tid & 63;
  int wr = w >> 1, wc = w & 1;
  f32x4 acc[4][2] = {};
  for (int k0 = 0; k0 < K; k0 += 64) {
    __syncthreads();
#pragma unroll
    for (int i = 0; i < 4; ++i) {
      int chunk = i * 4 + w;
      int d = chunk * 1024 + l * 16;
      int lg = d ^ (((d >> 7) & 7) << 4);
      int row = lg >> 7, kb = lg & 127;
      gload16((const char*)(A + (size_t)(m0 + row) * lda + k0) + kb, (char*)sA + chunk * 1024);
    }
#pragma unroll
    for (int i = 0; i < 2; ++i) {
      int chunk = i * 4 + w;
      int d = chunk * 1024 + l * 16;
      int lg = d ^ (((d >> 7) & 7) << 4);
      int row = lg >> 7, kb = lg & 127;
      gload16((const char*)(B + (size_t)(n0 + row) * ldb + k0) + kb, (char*)sB + chunk * 1024);
    }
    __syncthreads();
#pragma unroll
    for (int kk = 0; kk < 2; ++kk) {
      bf16x8 av[4], bv[2];
#pragma unroll
      for (int fm = 0; fm < 4; ++fm) {
        int row = wr * 64 + fm * 16 + (l & 15);
        int addr = (row * 128 + kk * 64 + (l >> 4) * 16) ^ ((row & 7) << 4);
        av[fm] = *(const bf16x8*)((const char*)sA + addr);
      }
#pragma unroll
      for (int fn = 0; fn < 2; ++fn) {
        int row = wc * 32 + fn * 16 + (l & 15);
        int addr = (row * 128 + kk * 64 + (l >> 4) * 16) ^ ((row & 7) << 4);
        bv[fn] = *(const bf16x8*)((const char*)sB + addr);
      }
#pragma unroll
      for (int fm = 0; fm < 4; ++fm)
#pragma unroll
        for (int fn = 0; fn < 2; ++fn)
          acc[fm][fn] = __builtin_amdgcn_mfma_f32_16x16x32_bf16(av[fm], bv[fn], acc[fm][fn], 0, 0, 0);
    }
  }
#pragma unroll
  for (int fn = 0; fn < 2; ++fn) {
    int c = n0 + wc * 32 + fn * 16 + (l & 15);
    float bb = bias ? bias[c] : 0.f;
#pragma unroll
    for (int fm = 0; fm < 4; ++fm) {
      int r = m0 + wr * 64 + fm * 16 + (l >> 4) * 4;
#pragma unroll
      for (int j = 0; j < 4; ++j) {
        float val = acc[fm][fn][j] + bb;
        if (B16OUT) ((u16*)outv)[(size_t)(r + j) * ldo + c] = f2b(val);
        else        ((float*)outv)[(size_t)(r + j) * ldo + c] = val;
      }
    }
  }
}

// ---------------- batched logits GEMM: bcat(31744x768) @ Wfc^T -> dout scatter ----
__global__ __launch_bounds__(256) void k_bgemm_logits(const u16* __restrict__ A,
                                                      const u16* __restrict__ B,
                                                      const float* __restrict__ bias,
                                                      float* __restrict__ dout) {
  __shared__ u16 sA[128 * 64];
  __shared__ u16 sB[64 * 64];
  int m0 = blockIdx.x * 128, n0 = blockIdx.y * 64;
  int tid = threadIdx.x, w = tid >> 6, l = tid & 63;
  int wr = w >> 1, wc = w & 1;
  f32x4 acc[4][2] = {};
  for (int k0 = 0; k0 < 768; k0 += 64) {
    __syncthreads();
#pragma unroll
    for (int i = 0; i < 4; ++i) {
      int chunk = i * 4 + w;
      int d = chunk * 1024 + l * 16;
      int lg = d ^ (((d >> 7) & 7) << 4);
      int row = lg >> 7, kb = lg & 127;
      gload16((const char*)(A + (size_t)(m0 + row) * 768 + k0) + kb, (char*)sA + chunk * 1024);
    }
#pragma unroll
    for (int i = 0; i < 2; ++i) {
      int chunk = i * 4 + w;
      int d = chunk * 1024 + l * 16;
      int lg = d ^ (((d >> 7) & 7) << 4);
      int row = lg >> 7, kb = lg & 127;
      gload16((const char*)(B + (size_t)(n0 + row) * 768 + k0) + kb, (char*)sB + chunk * 1024);
    }
    __syncthreads();
#pragma unroll
    for (int kk = 0; kk < 2; ++kk) {
      bf16x8 av[4], bv[2];
#pragma unroll
      for (int fm = 0; fm < 4; ++fm) {
        int row = wr * 64 + fm * 16 + (l & 15);
        int addr = (row * 128 + kk * 64 + (l >> 4) * 16) ^ ((row & 7) << 4);
        av[fm] = *(const bf16x8*)((const char*)sA + addr);
      }
#pragma unroll
      for (int fn = 0; fn < 2; ++fn) {
        int row = wc * 32 + fn * 16 + (l & 15);
        int addr = (row * 128 + kk * 64 + (l >> 4) * 16) ^ ((row & 7) << 4);
        bv[fn] = *(const bf16x8*)((const char*)sB + addr);
      }
#pragma unroll
      for (int fm = 0; fm < 4; ++fm)
#pragma unroll
        for (int fn = 0; fn < 2; ++fn)
          acc[fm][fn] = __builtin_amdgcn_mfma_f32_16x16x32_bf16(av[fm], bv[fn], acc[fm][fn], 0, 0, 0);
    }
  }
#pragma unroll
  for (int fn = 0; fn < 2; ++fn) {
    int c = n0 + wc * 32 + fn * 16 + (l & 15);
    float bb = bias[c];
#pragma unroll
    for (int fm = 0; fm < 4; ++fm) {
#pragma unroll
      for (int j = 0; j < 4; ++j) {
        int gr = m0 + wr * 64 + fm * 16 + (l >> 4) * 4 + j;
        int tt = gr >> 10, b = gr & 1023;
        dout[(size_t)b * (TLEN * 256) + (size_t)(tt + 1) * 256 + c] = acc[fm][fn][j] + bb;
      }
    }
  }
}

// ---------------- persistent encoder: 64 blocks x 16 rows, 16 waves --------------
struct EncArgs {
  u16* enc_b; u16* hcatB; const int* src;
  const u16* Whhf; const u16* Whhb;
  const float* bhhf; const float* bhhb;
  const float* tabf; const float* tabb;
};

__global__ __launch_bounds__(1024) void k_enc_p(EncArgs E) {
  __shared__ float hF[2][16 * HFLD];
  __shared__ u16 hB[2][16 * HLD];
  __shared__ int toks[512];
  int r0 = blockIdx.x * 16;
  int tid = threadIdx.x, w = tid >> 6, l = tid & 63;
  int dir = w >> 3, wc = w & 7;  // wave: direction + 32-col slice
  for (int i = tid; i < 16 * 256; i += 1024) {
    int r = i >> 8, c = i & 255;
    hF[0][r * HFLD + c] = 0.f; hF[1][r * HFLD + c] = 0.f;
    hB[0][r * HLD + c] = 0;    hB[1][r * HLD + c] = 0;
  }
  if (tid < 512) toks[tid] = E.src[(size_t)(r0 + (tid >> 5)) * SLEN + (tid & 31)];
  __syncthreads();
  const u16* Whh = dir ? E.Whhb : E.Whhf;
  const float* tab = dir ? E.tabb : E.tabf;
  const float* bhh = dir ? E.bhhb : E.bhhf;
  for (int s = 0; s < SLEN; ++s) {
    int s_store = dir ? (SLEN - 1 - s) : s;
    f32x4 ae[3][2] = {};
    if (s > 0) {
      for (int k0 = 0; k0 < 256; k0 += 32) {
        bf16x8 av = *(const bf16x8*)(hB[dir] + (l & 15) * HLD + k0 + (l >> 4) * 8);
#pragma unroll
        for (int g = 0; g < 3; ++g)
#pragma unroll
          for (int fn = 0; fn < 2; ++fn) {
            bf16x8 bv = *(const bf16x8*)(Whh + (size_t)(g * 256 + wc * 32 + fn * 16 + (l & 15)) * 256 + k0 + (l >> 4) * 8);
            ae[g][fn] = __builtin_amdgcn_mfma_f32_16x16x32_bf16(av, bv, ae[g][fn], 0, 0, 0);
          }
      }
    }
    __syncthreads();
#pragma unroll
    for (int fn = 0; fn < 2; ++fn) {
      int c = wc * 32 + fn * 16 + (l & 15);
      float bR = bhh[c], bZ = bhh[256 + c], bN = bhh[512 + c];
#pragma unroll
      for (int j = 0; j < 4; ++j) {
        int row = (l >> 4) * 4 + j;
        const float* tb = tab + (size_t)toks[row * 32 + s_store] * 768 + c;
        float rg = sgm(tb[0] + ae[0][fn][j] + bR);
        float zg = sgm(tb[256] + ae[1][fn][j] + bZ);
        float ng = tanh_fast(tb[512] + rg * (ae[2][fn][j] + bN));
        float hold = hF[dir][row * HFLD + c];
        float hv = (1.f - zg) * ng + zg * hold;
        hF[dir][row * HFLD + c] = hv;
        u16 hb16 = f2b(hv);
        hB[dir][row * HLD + c] = hb16;
        __builtin_nontemporal_store(
            hb16, E.enc_b + ((size_t)(r0 + row) * SLEN + s_store) * 512 + dir * 256 + c);
      }
    }
    __syncthreads();
  }
  for (int i = tid; i < 16 * 512; i += 1024) {
    int r = i >> 9, c = i & 511;
    E.hcatB[(size_t)(r0 + r) * 512 + c] =
        (c < 256) ? hB[0][r * HLD + c] : hB[1][r * HLD + (c - 256)];
  }
}

// ---------------- persistent decoder: 64 blocks x 16 rows, 16 waves --------------
struct DecArgs {
  const u16* enc_b; const u16* enc_pre_b; const float* v_attn;
  const u16* Wd_b; const u16* Wg;
  const float* tabd; const float* dbhh;
  const int* trg; const float* h0f;
  u16* bcat;
};

__global__ __launch_bounds__(1024) void k_dec_p(DecArgs A) {
  __shared__ float hF[16 * HFLD];
  __shared__ u16 hB[16 * HLD];
  __shared__ u16 ctxB[16 * CTXLD];
  __shared__ float hwS[16 * HWLD];
  __shared__ float awS[16 * 33];
  __shared__ float vS[256];
  __shared__ int toks[512];
  int r0 = blockIdx.x * 16;
  int tid = threadIdx.x, w = tid >> 6, l = tid & 63;
  for (int i = tid; i < 16 * 256; i += 1024) {
    int r = i >> 8, c = i & 255;
    float v = A.h0f[(size_t)(r0 + r) * 256 + c];
    hF[r * HFLD + c] = v;
    hB[r * HLD + c] = f2b(v);
  }
  if (tid < 256) vS[tid] = A.v_attn[tid];
  if (tid < 512) toks[tid] = A.trg[(size_t)(r0 + (tid >> 5)) * TLEN + (tid & 31)];
  __syncthreads();
  for (int t = 0; t < TLEN - 1; ++t) {
    // ---- P1: hWd = h @ Wd^T : wave w -> cols [w*16, w*16+16) ----
    {
      f32x4 a1 = {};
      for (int k0 = 0; k0 < 256; k0 += 32) {
        bf16x8 av = *(const bf16x8*)(hB + (l & 15) * HLD + k0 + (l >> 4) * 8);
        bf16x8 bv = *(const bf16x8*)(A.Wd_b + (size_t)(w * 16 + (l & 15)) * 256 + k0 + (l >> 4) * 8);
        a1 = __builtin_amdgcn_mfma_f32_16x16x32_bf16(av, bv, a1, 0, 0, 0);
      }
      int c = w * 16 + (l & 15);
#pragma unroll
      for (int j = 0; j < 4; ++j)
        hwS[((l >> 4) * 4 + j) * HWLD + c] = a1[j];
    }
    __syncthreads();
    // ---- P2: scores + softmax: wave w -> row w; lane: s = l>>1, half = l&1 ----
    {
      int r = w, s = l >> 1, half = l & 1;
      const u16* ep = A.enc_pre_b + ((size_t)(r0 + r) * SLEN + s) * 256 + half * 128;
      const float* hw = hwS + r * HWLD + half * 128;
      const float* vv = vS + half * 128;
      float sum = 0.f;
      for (int a0 = 0; a0 < 128; a0 += 8) {
        bf16x8 pk = __builtin_nontemporal_load((const bf16x8*)(ep + a0));
#pragma unroll
        for (int q = 0; q < 8; ++q)
          sum += vv[a0 + q] * tanh_fast(b2f((u16)pk[q]) + hw[a0 + q]);
      }
      sum += __shfl_xor(sum, 1);
      float m = sum;
#pragma unroll
      for (int o = 2; o <= 32; o <<= 1) m = fmaxf(m, __shfl_xor(m, o));
      float e = __expf(sum - m), ss = e;
#pragma unroll
      for (int o = 2; o <= 32; o <<= 1) ss += __shfl_xor(ss, o);
      if (half == 0) awS[r * 33 + s] = e / ss;
    }
    __syncthreads();
    // ---- P3: ctx = aw @ enc_b : thread -> (r = tid>>6, c8 = tid&63) ----
    {
      int r = tid >> 6, c = (tid & 63) * 8;
      float a8[8] = {};
      const u16* eb = A.enc_b + ((size_t)(r0 + r) * SLEN) * 512 + c;
#pragma unroll 4
      for (int s2 = 0; s2 < 32; ++s2) {
        float a = awS[r * 33 + s2];
        bf16x8 pk = __builtin_nontemporal_load((const bf16x8*)(eb + s2 * 512));
#pragma unroll
        for (int q = 0; q < 8; ++q) a8[q] += a * b2f((u16)pk[q]);
      }
      bf16x8 o;
#pragma unroll
      for (int q = 0; q < 8; ++q) o[q] = (short)f2b(a8[q]);
      *(bf16x8*)(ctxB + r * CTXLD + c) = o;
      __builtin_nontemporal_store(
          o, (bf16x8*)(A.bcat + ((size_t)t * BSZ + r0 + r) * 768 + 256 + c));
    }
    __syncthreads();
    // ---- P4: gates: wave w -> hidden cols [w*16, +16), 4 gate groups ----
    f32x4 ag[4] = {};
    for (int k0 = 0; k0 < 768; k0 += 32) {
      bf16x8 av = (k0 < 512)
          ? *(const bf16x8*)(ctxB + (l & 15) * CTXLD + k0 + (l >> 4) * 8)
          : *(const bf16x8*)(hB + (l & 15) * HLD + (k0 - 512) + (l >> 4) * 8);
#pragma unroll
      for (int g = 0; g < 4; ++g) {
        bf16x8 bv = *(const bf16x8*)(A.Wg + (size_t)(g * 256 + w * 16 + (l & 15)) * 768 + k0 + (l >> 4) * 8);
        ag[g] = __builtin_amdgcn_mfma_f32_16x16x32_bf16(av, bv, ag[g], 0, 0, 0);
      }
    }
    __syncthreads();
    // ---- P5: GRU epilogue: wave w -> col c = w*16 + (l&15) ----
    {
      int c = w * 16 + (l & 15);
      float bR = A.dbhh[c], bZ = A.dbhh[256 + c], bN = A.dbhh[512 + c];
#pragma unroll
      for (int j = 0; j < 4; ++j) {
        int row = (l >> 4) * 4 + j;
        const float* tb = A.tabd + (size_t)toks[row * 32 + t] * 768 + c;
        float rg = sgm(tb[0] + ag[0][j] + bR);
        float zg = sgm(tb[256] + ag[1][j] + bZ);
        float ng = tanh_fast(tb[512] + ag[2][j] + rg * (ag[3][j] + bN));
        float hold = hF[row * HFLD + c];
        float hv = (1.f - zg) * ng + zg * hold;
        hF[row * HFLD + c] = hv;
        u16 hb16 = f2b(hv);
        hB[row * HLD + c] = hb16;
        __builtin_nontemporal_store(hb16,
                                    A.bcat + ((size_t)t * BSZ + r0 + row) * 768 + c);
      }
    }
    __syncthreads();
  }
}

// ---------------- zero t=0 slice -------------------------------------------------
__global__ __launch_bounds__(256) void k_zero0(float* __restrict__ outp) {
  outp[(size_t)blockIdx.x * (TLEN * 256) + threadIdx.x] = 0.f;
}

extern "C" void kernel_launch(void* const* d_in, const int* in_sizes, int n_in,
                              void* d_out, int out_size, void* d_ws, size_t ws_size,
                              hipStream_t stream) {
  (void)in_sizes; (void)n_in; (void)out_size; (void)ws_size;
  const int* src = (const int*)d_in[0];
  const int* trg = (const int*)d_in[1];
  const float* enc_emb = (const float*)d_in[2];
  const float* eWih_f = (const float*)d_in[3];
  const float* eWhh_f = (const float*)d_in[4];
  const float* ebih_f = (const float*)d_in[5];
  const float* ebhh_f = (const float*)d_in[6];
  const float* eWih_b = (const float*)d_in[7];
  const float* eWhh_b = (const float*)d_in[8];
  const float* ebih_b = (const float*)d_in[9];
  const float* ebhh_b = (const float*)d_in[10];
  const float* Wproj = (const float*)d_in[11];
  const float* bproj = (const float*)d_in[12];
  const float* dec_emb = (const float*)d_in[13];
  const float* Wattn = (const float*)d_in[14];
  const float* battn = (const float*)d_in[15];
  const float* v_attn = (const float*)d_in[16];
  const float* dWih = (const float*)d_in[17];
  const float* dWhh = (const float*)d_in[18];
  const float* dbih = (const float*)d_in[19];
  const float* dbhh = (const float*)d_in[20];
  const float* Wfc = (const float*)d_in[21];
  const float* bfc = (const float*)d_in[22];
  float* dout = (float*)d_out;

  char* base = (char*)d_ws;
  size_t off = 0;
  auto alloc = [&](size_t bytes) {
    void* p = base + off;
    off += (bytes + 255) & ~(size_t)255;
    return p;
  };
  u16* enc_b     = (u16*)alloc((size_t)BSZ * SLEN * 512 * 2);
  u16* enc_pre_b = (u16*)alloc((size_t)BSZ * SLEN * 256 * 2);
  u16* bcat      = (u16*)alloc((size_t)31 * BSZ * 768 * 2);
  float* tabf    = (float*)alloc((size_t)64 * 768 * 4);
  float* tabb    = (float*)alloc((size_t)64 * 768 * 4);
  float* tabd    = (float*)alloc((size_t)256 * 768 * 4);
  u16* hcatB     = (u16*)alloc((size_t)BSZ * 512 * 2);
  float* h0f     = (float*)alloc((size_t)BSZ * 256 * 4);
  u16* Whhf_b    = (u16*)alloc((size_t)768 * 256 * 2);
  u16* Whhb_b    = (u16*)alloc((size_t)768 * 256 * 2);
  u16* We_b      = (u16*)alloc((size_t)256 * 512 * 2);
  u16* Wd_b      = (u16*)alloc((size_t)256 * 256 * 2);
  u16* Wproj_b   = (u16*)alloc((size_t)256 * 512 * 2);
  u16* Wg        = (u16*)alloc((size_t)1024 * 768 * 2);
  u16* Wfc_b     = (u16*)alloc((size_t)256 * 768 * 2);

  // tables + weight packs
  k_gi_table<<<dim3(64, 3), 256, 0, stream>>>(enc_emb, eWih_f, EDIM, ebih_f, tabf);
  k_gi_table<<<dim3(64, 3), 256, 0, stream>>>(enc_emb, eWih_b, EDIM, ebih_b, tabb);
  k_gi_table<<<dim3(256, 3), 256, 0, stream>>>(dec_emb, dWih, 640, dbih, tabd);
  k_pack<<<dim3(768), 256, 0, stream>>>(Whhf_b, eWhh_f, 256, 0, 256);
  k_pack<<<dim3(768), 256, 0, stream>>>(Whhb_b, eWhh_b, 256, 0, 256);
  k_pack<<<dim3(256), 256, 0, stream>>>(We_b, Wattn, 768, 256, 512);
  k_pack<<<dim3(256), 256, 0, stream>>>(Wd_b, Wattn, 768, 0, 256);
  k_pack<<<dim3(256), 256, 0, stream>>>(Wproj_b, Wproj, 512, 0, 512);
  k_pack<<<dim3(256), 256, 0, stream>>>(Wfc_b, Wfc, 768, 0, 768);
  k_pack_gates<<<dim3(1024), 256, 0, stream>>>(Wg, dWih, dWhh);

  // encoder: persistent, 64 blocks x 1024 threads, zero grid sync
  {
    EncArgs ea{enc_b, hcatB, src, Whhf_b, Whhb_b, ebhh_f, ebhh_b, tabf, tabb};
    k_enc_p<<<dim3(64), dim3(1024), 0, stream>>>(ea);
  }

  // hdec = hcat @ Wproj^T + bproj (fp32 out)
  k_bgemm<false><<<dim3(8, 4), 256, 0, stream>>>(hcatB, 512, Wproj_b, 512, bproj, h0f, 256, 512);
  // enc_pre (bf16) = enc_b @ We^T + battn
  k_bgemm<true><<<dim3(256, 4), 256, 0, stream>>>(enc_b, 512, We_b, 512, battn,
                                                  enc_pre_b, 256, 512);
  k_zero0<<<dim3(BSZ), 256, 0, stream>>>(dout);

  // decoder: persistent, 64 blocks x 1024 threads, zero grid sync
  {
    DecArgs da{enc_b, enc_pre_b, v_attn, Wd_b, Wg, tabd, dbhh, trg, h0f, bcat};
    k_dec_p<<<dim3(64), dim3(1024), 0, stream>>>(da);
  }

  // deferred logits: [hn|ctx] @ Wfc^T + bfc for all 31 steps at once
  k_bgemm_logits<<<dim3(248, 4), 256, 0, stream>>>(bcat, Wfc_b, bfc, dout);
}

// Round 9
// 2944.902 us; speedup vs baseline: 1.5039x; 1.5039x over previous
//
#include <hip/hip_runtime.h>
#include <math.h>

#define BSZ 1024
#define SLEN 32
#define TLEN 32
#define EDIM 128
#define HLD 264    // u16 row stride for bf16 h in LDS
#define HFLD 260   // f32 row stride
#define CTXLD 520  // u16 row stride for ctx
#define HWLD 260   // f32 row stride for hWd

typedef unsigned short u16;
typedef __attribute__((ext_vector_type(8))) short bf16x8;
typedef __attribute__((ext_vector_type(4))) float f32x4;

__device__ __forceinline__ float sgm(float x) { return 1.0f / (1.0f + __expf(-x)); }
__device__ __forceinline__ float tanh_fast(float x) {
  float e = __expf(-2.0f * fabsf(x));
  float t = (1.0f - e) / (1.0f + e);
  return copysignf(t, x);
}
__device__ __forceinline__ u16 f2b(float f) {
  union { float f; unsigned u; } v; v.f = f;
  unsigned r = v.u + 0x7fffu + ((v.u >> 16) & 1u);
  return (u16)(r >> 16);
}
__device__ __forceinline__ float b2f(u16 h) {
  union { unsigned u; float f; } v; v.u = ((unsigned)h) << 16; return v.f;
}

typedef __attribute__((address_space(1))) const void gv_t;
typedef __attribute__((address_space(3))) void lv_t;
__device__ __forceinline__ void gload16(const void* g, void* l) {
  __builtin_amdgcn_global_load_lds((gv_t*)g, (lv_t*)l, 16, 0, 0);
}

// ---------------- gi tables -------------------------------------------------------
__global__ __launch_bounds__(256) void k_gi_table(const float* __restrict__ emb,
                                                  const float* __restrict__ Wih, int ldw,
                                                  const float* __restrict__ bih,
                                                  float* __restrict__ tab) {
  int v = blockIdx.x;
  int g = blockIdx.y * 256 + threadIdx.x;
  __shared__ float e[EDIM];
  if (threadIdx.x < EDIM) e[threadIdx.x] = emb[v * EDIM + threadIdx.x];
  __syncthreads();
  const float4* w4 = (const float4*)(Wih + (size_t)g * ldw);
  float acc = 0.f;
#pragma unroll
  for (int j = 0; j < EDIM / 4; ++j) {
    float4 w = w4[j];
    acc += w.x * e[4 * j] + w.y * e[4 * j + 1] + w.z * e[4 * j + 2] + w.w * e[4 * j + 3];
  }
  tab[(size_t)v * 768 + g] = acc + bih[g];
}

// ---------------- fp32 -> bf16 weight pack ---------------------------------------
__global__ __launch_bounds__(256) void k_pack(u16* __restrict__ dst,
                                              const float* __restrict__ src, int ld,
                                              int off, int n) {
  int r = blockIdx.x;
  for (int c = threadIdx.x; c < n; c += 256)
    dst[(size_t)r * n + c] = f2b(src[(size_t)r * ld + off + c]);
}

// ---------------- bf16 MFMA GEMM 128x64: out = A.B^T + bias ----------------------
template <bool B16OUT>
__global__ __launch_bounds__(256) void k_bgemm(const u16* __restrict__ A, int lda,
                                               const u16* __restrict__ B, int ldb,
                                               const float* __restrict__ bias,
                                               void* __restrict__ outv, int ldo, int K) {
  __shared__ u16 sA[128 * 64];
  __shared__ u16 sB[64 * 64];
  int m0 = blockIdx.x * 128, n0 = blockIdx.y * 64;
  int tid = threadIdx.x, w = tid >> 6, l = tid & 63;
  int wr = w >> 1, wc = w & 1;
  f32x4 acc[4][2] = {};
  for (int k0 = 0; k0 < K; k0 += 64) {
    __syncthreads();
#pragma unroll
    for (int i = 0; i < 4; ++i) {
      int chunk = i * 4 + w;
      int d = chunk * 1024 + l * 16;
      int lg = d ^ (((d >> 7) & 7) << 4);
      int row = lg >> 7, kb = lg & 127;
      gload16((const char*)(A + (size_t)(m0 + row) * lda + k0) + kb, (char*)sA + chunk * 1024);
    }
#pragma unroll
    for (int i = 0; i < 2; ++i) {
      int chunk = i * 4 + w;
      int d = chunk * 1024 + l * 16;
      int lg = d ^ (((d >> 7) & 7) << 4);
      int row = lg >> 7, kb = lg & 127;
      gload16((const char*)(B + (size_t)(n0 + row) * ldb + k0) + kb, (char*)sB + chunk * 1024);
    }
    __syncthreads();
#pragma unroll
    for (int kk = 0; kk < 2; ++kk) {
      bf16x8 av[4], bv[2];
#pragma unroll
      for (int fm = 0; fm < 4; ++fm) {
        int row = wr * 64 + fm * 16 + (l & 15);
        int addr = (row * 128 + kk * 64 + (l >> 4) * 16) ^ ((row & 7) << 4);
        av[fm] = *(const bf16x8*)((const char*)sA + addr);
      }
#pragma unroll
      for (int fn = 0; fn < 2; ++fn) {
        int row = wc * 32 + fn * 16 + (l & 15);
        int addr = (row * 128 + kk * 64 + (l >> 4) * 16) ^ ((row & 7) << 4);
        bv[fn] = *(const bf16x8*)((const char*)sB + addr);
      }
#pragma unroll
      for (int fm = 0; fm < 4; ++fm)
#pragma unroll
        for (int fn = 0; fn < 2; ++fn)
          acc[fm][fn] = __builtin_amdgcn_mfma_f32_16x16x32_bf16(av[fm], bv[fn], acc[fm][fn], 0, 0, 0);
    }
  }
#pragma unroll
  for (int fn = 0; fn < 2; ++fn) {
    int c = n0 + wc * 32 + fn * 16 + (l & 15);
    float bb = bias ? bias[c] : 0.f;
#pragma unroll
    for (int fm = 0; fm < 4; ++fm) {
      int r = m0 + wr * 64 + fm * 16 + (l >> 4) * 4;
#pragma unroll
      for (int j = 0; j < 4; ++j) {
        float val = acc[fm][fn][j] + bb;
        if (B16OUT) ((u16*)outv)[(size_t)(r + j) * ldo + c] = f2b(val);
        else        ((float*)outv)[(size_t)(r + j) * ldo + c] = val;
      }
    }
  }
}

// ---------------- batched logits GEMM: bcat(31744x768) @ Wfc^T -> dout scatter ----
__global__ __launch_bounds__(256) void k_bgemm_logits(const u16* __restrict__ A,
                                                      const u16* __restrict__ B,
                                                      const float* __restrict__ bias,
                                                      float* __restrict__ dout) {
  __shared__ u16 sA[128 * 64];
  __shared__ u16 sB[64 * 64];
  int m0 = blockIdx.x * 128, n0 = blockIdx.y * 64;
  int tid = threadIdx.x, w = tid >> 6, l = tid & 63;
  int wr = w >> 1, wc = w & 1;
  f32x4 acc[4][2] = {};
  for (int k0 = 0; k0 < 768; k0 += 64) {
    __syncthreads();
#pragma unroll
    for (int i = 0; i < 4; ++i) {
      int chunk = i * 4 + w;
      int d = chunk * 1024 + l * 16;
      int lg = d ^ (((d >> 7) & 7) << 4);
      int row = lg >> 7, kb = lg & 127;
      gload16((const char*)(A + (size_t)(m0 + row) * 768 + k0) + kb, (char*)sA + chunk * 1024);
    }
#pragma unroll
    for (int i = 0; i < 2; ++i) {
      int chunk = i * 4 + w;
      int d = chunk * 1024 + l * 16;
      int lg = d ^ (((d >> 7) & 7) << 4);
      int row = lg >> 7, kb = lg & 127;
      gload16((const char*)(B + (size_t)(n0 + row) * 768 + k0) + kb, (char*)sB + chunk * 1024);
    }
    __syncthreads();
#pragma unroll
    for (int kk = 0; kk < 2; ++kk) {
      bf16x8 av[4], bv[2];
#pragma unroll
      for (int fm = 0; fm < 4; ++fm) {
        int row = wr * 64 + fm * 16 + (l & 15);
        int addr = (row * 128 + kk * 64 + (l >> 4) * 16) ^ ((row & 7) << 4);
        av[fm] = *(const bf16x8*)((const char*)sA + addr);
      }
#pragma unroll
      for (int fn = 0; fn < 2; ++fn) {
        int row = wc * 32 + fn * 16 + (l & 15);
        int addr = (row * 128 + kk * 64 + (l >> 4) * 16) ^ ((row & 7) << 4);
        bv[fn] = *(const bf16x8*)((const char*)sB + addr);
      }
#pragma unroll
      for (int fm = 0; fm < 4; ++fm)
#pragma unroll
        for (int fn = 0; fn < 2; ++fn)
          acc[fm][fn] = __builtin_amdgcn_mfma_f32_16x16x32_bf16(av[fm], bv[fn], acc[fm][fn], 0, 0, 0);
    }
  }
#pragma unroll
  for (int fn = 0; fn < 2; ++fn) {
    int c = n0 + wc * 32 + fn * 16 + (l & 15);
    float bb = bias[c];
#pragma unroll
    for (int fm = 0; fm < 4; ++fm) {
#pragma unroll
      for (int j = 0; j < 4; ++j) {
        int gr = m0 + wr * 64 + fm * 16 + (l >> 4) * 4 + j;
        int tt = gr >> 10, b = gr & 1023;
        dout[(size_t)b * (TLEN * 256) + (size_t)(tt + 1) * 256 + c] = acc[fm][fn][j] + bb;
      }
    }
  }
}

// ---------------- persistent encoder: 64 blocks x 16 rows, 16 waves --------------
struct EncArgs {
  u16* enc_b; u16* hcatB; const int* src;
  const u16* Whhf; const u16* Whhb;
  const float* bhhf; const float* bhhb;
  const float* tabf; const float* tabb;
};

__global__ __launch_bounds__(1024) void k_enc_p(EncArgs E) {
  __shared__ float hF[2][16 * HFLD];
  __shared__ u16 hB[2][16 * HLD];
  __shared__ int toks[512];
  int r0 = blockIdx.x * 16;
  int tid = threadIdx.x, w = tid >> 6, l = tid & 63;
  int dir = w >> 3, wc = w & 7;  // wave: direction + 32-col slice
  for (int i = tid; i < 16 * 256; i += 1024) {
    int r = i >> 8, c = i & 255;
    hF[0][r * HFLD + c] = 0.f; hF[1][r * HFLD + c] = 0.f;
    hB[0][r * HLD + c] = 0;    hB[1][r * HLD + c] = 0;
  }
  if (tid < 512) toks[tid] = E.src[(size_t)(r0 + (tid >> 5)) * SLEN + (tid & 31)];
  __syncthreads();
  const u16* Whh = dir ? E.Whhb : E.Whhf;
  const float* tab = dir ? E.tabb : E.tabf;
  const float* bhh = dir ? E.bhhb : E.bhhf;
  for (int s = 0; s < SLEN; ++s) {
    int s_store = dir ? (SLEN - 1 - s) : s;
    f32x4 ae[3][2] = {};
    if (s > 0) {
      // depth-3 register prefetch ring over 8 k-iters
      bf16x8 pw[3][3][2];
#pragma unroll
      for (int r = 0; r < 3; ++r)
#pragma unroll
        for (int g = 0; g < 3; ++g)
#pragma unroll
          for (int fn = 0; fn < 2; ++fn)
            pw[r][g][fn] = *(const bf16x8*)(Whh +
                (size_t)(g * 256 + wc * 32 + fn * 16 + (l & 15)) * 256 + r * 32 + (l >> 4) * 8);
#pragma unroll
      for (int kk = 0; kk < 8; ++kk) {
        int slot = kk % 3;
        bf16x8 av = *(const bf16x8*)(hB[dir] + (l & 15) * HLD + kk * 32 + (l >> 4) * 8);
#pragma unroll
        for (int g = 0; g < 3; ++g)
#pragma unroll
          for (int fn = 0; fn < 2; ++fn)
            ae[g][fn] = __builtin_amdgcn_mfma_f32_16x16x32_bf16(av, pw[slot][g][fn], ae[g][fn], 0, 0, 0);
        if (kk + 3 < 8) {
#pragma unroll
          for (int g = 0; g < 3; ++g)
#pragma unroll
            for (int fn = 0; fn < 2; ++fn)
              pw[slot][g][fn] = *(const bf16x8*)(Whh +
                  (size_t)(g * 256 + wc * 32 + fn * 16 + (l & 15)) * 256 + (kk + 3) * 32 + (l >> 4) * 8);
        }
      }
    }
    __syncthreads();
#pragma unroll
    for (int fn = 0; fn < 2; ++fn) {
      int c = wc * 32 + fn * 16 + (l & 15);
      float bR = bhh[c], bZ = bhh[256 + c], bN = bhh[512 + c];
#pragma unroll
      for (int j = 0; j < 4; ++j) {
        int row = (l >> 4) * 4 + j;
        const float* tb = tab + (size_t)toks[row * 32 + s_store] * 768 + c;
        float rg = sgm(tb[0] + ae[0][fn][j] + bR);
        float zg = sgm(tb[256] + ae[1][fn][j] + bZ);
        float ng = tanh_fast(tb[512] + rg * (ae[2][fn][j] + bN));
        float hold = hF[dir][row * HFLD + c];
        float hv = (1.f - zg) * ng + zg * hold;
        hF[dir][row * HFLD + c] = hv;
        u16 hb16 = f2b(hv);
        hB[dir][row * HLD + c] = hb16;
        __builtin_nontemporal_store(
            hb16, E.enc_b + ((size_t)(r0 + row) * SLEN + s_store) * 512 + dir * 256 + c);
      }
    }
    __syncthreads();
  }
  for (int i = tid; i < 16 * 512; i += 1024) {
    int r = i >> 9, c = i & 511;
    E.hcatB[(size_t)(r0 + r) * 512 + c] =
        (c < 256) ? hB[0][r * HLD + c] : hB[1][r * HLD + (c - 256)];
  }
}

// ---------------- persistent decoder: 64 blocks x 16 rows, 16 waves --------------
struct DecArgs {
  const u16* enc_b; const u16* enc_pre_b; const float* v_attn;
  const u16* Wd_b; const u16* Wg_lo; const u16* Wg_hi;
  const float* tabd; const float* dbhh;
  const int* trg; const float* h0f;
  u16* bcat;
};

__global__ __launch_bounds__(1024) void k_dec_p(DecArgs A) {
  __shared__ float hF[16 * HFLD];
  __shared__ u16 hB[16 * HLD];
  __shared__ u16 ctxB[16 * CTXLD];
  __shared__ float hwS[16 * HWLD];
  __shared__ float awS[16 * 33];
  __shared__ float vS[256];
  __shared__ int toks[512];
  int r0 = blockIdx.x * 16;
  int tid = threadIdx.x, w = tid >> 6, l = tid & 63;
  for (int i = tid; i < 16 * 256; i += 1024) {
    int r = i >> 8, c = i & 255;
    float v = A.h0f[(size_t)(r0 + r) * 256 + c];
    hF[r * HFLD + c] = v;
    hB[r * HLD + c] = f2b(v);
  }
  if (tid < 256) vS[tid] = A.v_attn[tid];
  if (tid < 512) toks[tid] = A.trg[(size_t)(r0 + (tid >> 5)) * TLEN + (tid & 31)];
  __syncthreads();
  for (int t = 0; t < TLEN - 1; ++t) {
    // ---- P1: hWd = h @ Wd^T : wave w -> cols [w*16, w*16+16), depth-4 ring ----
    {
      f32x4 a1 = {};
      bf16x8 pw[4];
#pragma unroll
      for (int r = 0; r < 4; ++r)
        pw[r] = *(const bf16x8*)(A.Wd_b + (size_t)(w * 16 + (l & 15)) * 256 + r * 32 + (l >> 4) * 8);
#pragma unroll
      for (int kk = 0; kk < 8; ++kk) {
        int slot = kk % 4;
        bf16x8 av = *(const bf16x8*)(hB + (l & 15) * HLD + kk * 32 + (l >> 4) * 8);
        a1 = __builtin_amdgcn_mfma_f32_16x16x32_bf16(av, pw[slot], a1, 0, 0, 0);
        if (kk + 4 < 8)
          pw[slot] = *(const bf16x8*)(A.Wd_b + (size_t)(w * 16 + (l & 15)) * 256 + (kk + 4) * 32 + (l >> 4) * 8);
      }
      int c = w * 16 + (l & 15);
#pragma unroll
      for (int j = 0; j < 4; ++j)
        hwS[((l >> 4) * 4 + j) * HWLD + c] = a1[j];
    }
    __syncthreads();
    // ---- P2: scores + softmax: wave w -> row w; lane: s = l>>1, half = l&1 ----
    {
      int r = w, s = l >> 1, half = l & 1;
      const u16* ep = A.enc_pre_b + ((size_t)(r0 + r) * SLEN + s) * 256 + half * 128;
      const float* hw = hwS + r * HWLD + half * 128;
      const float* vv = vS + half * 128;
      float sum = 0.f;
      for (int a0 = 0; a0 < 128; a0 += 8) {
        bf16x8 pk = *(const bf16x8*)(ep + a0);
#pragma unroll
        for (int q = 0; q < 8; ++q)
          sum += vv[a0 + q] * tanh_fast(b2f((u16)pk[q]) + hw[a0 + q]);
      }
      sum += __shfl_xor(sum, 1);
      float m = sum;
#pragma unroll
      for (int o = 2; o <= 32; o <<= 1) m = fmaxf(m, __shfl_xor(m, o));
      float e = __expf(sum - m), ss = e;
#pragma unroll
      for (int o = 2; o <= 32; o <<= 1) ss += __shfl_xor(ss, o);
      if (half == 0) awS[r * 33 + s] = e / ss;
    }
    __syncthreads();
    // ---- P3: ctx = aw @ enc_b : thread -> (r = tid>>6, c8 = tid&63) ----
    {
      int r = tid >> 6, c = (tid & 63) * 8;
      float a8[8] = {};
      const u16* eb = A.enc_b + ((size_t)(r0 + r) * SLEN) * 512 + c;
#pragma unroll 4
      for (int s2 = 0; s2 < 32; ++s2) {
        float a = awS[r * 33 + s2];
        bf16x8 pk = *(const bf16x8*)(eb + s2 * 512);
#pragma unroll
        for (int q = 0; q < 8; ++q) a8[q] += a * b2f((u16)pk[q]);
      }
      bf16x8 o;
#pragma unroll
      for (int q = 0; q < 8; ++q) o[q] = (short)f2b(a8[q]);
      *(bf16x8*)(ctxB + r * CTXLD + c) = o;
      __builtin_nontemporal_store(
          o, (bf16x8*)(A.bcat + ((size_t)t * BSZ + r0 + r) * 768 + 256 + c));
    }
    __syncthreads();
    // ---- P4: gates, depth-6 register ring over 24 k-iters ----
    // kk<16: A=ctx, B=Wg_lo (gb: 0=R,1=Z,2=Ni). kk>=16: A=h, B=Wg_hi (gb: 0=R,1=Z,2=Nh->ag[3])
    f32x4 ag[4] = {};
    {
      bf16x8 pf[6][3];
#pragma unroll
      for (int r = 0; r < 6; ++r)
#pragma unroll
        for (int gb = 0; gb < 3; ++gb)
          pf[r][gb] = *(const bf16x8*)(A.Wg_lo +
              (size_t)(gb * 256 + w * 16 + (l & 15)) * 512 + r * 32 + (l >> 4) * 8);
#pragma unroll
      for (int kk = 0; kk < 24; ++kk) {
        int slot = kk % 6;
        bf16x8 av = (kk < 16)
            ? *(const bf16x8*)(ctxB + (l & 15) * CTXLD + kk * 32 + (l >> 4) * 8)
            : *(const bf16x8*)(hB + (l & 15) * HLD + (kk - 16) * 32 + (l >> 4) * 8);
#pragma unroll
        for (int gb = 0; gb < 3; ++gb) {
          int ai = (kk < 16) ? gb : (gb == 2 ? 3 : gb);
          ag[ai] = __builtin_amdgcn_mfma_f32_16x16x32_bf16(av, pf[slot][gb], ag[ai], 0, 0, 0);
        }
        int kn = kk + 6;
        if (kn < 24) {
#pragma unroll
          for (int gb = 0; gb < 3; ++gb) {
            if (kn < 16)
              pf[slot][gb] = *(const bf16x8*)(A.Wg_lo +
                  (size_t)(gb * 256 + w * 16 + (l & 15)) * 512 + kn * 32 + (l >> 4) * 8);
            else
              pf[slot][gb] = *(const bf16x8*)(A.Wg_hi +
                  (size_t)(gb * 256 + w * 16 + (l & 15)) * 256 + (kn - 16) * 32 + (l >> 4) * 8);
          }
        }
      }
    }
    __syncthreads();
    // ---- P5: GRU epilogue: wave w -> col c = w*16 + (l&15) ----
    {
      int c = w * 16 + (l & 15);
      float bR = A.dbhh[c], bZ = A.dbhh[256 + c], bN = A.dbhh[512 + c];
#pragma unroll
      for (int j = 0; j < 4; ++j) {
        int row = (l >> 4) * 4 + j;
        const float* tb = A.tabd + (size_t)toks[row * 32 + t] * 768 + c;
        float rg = sgm(tb[0] + ag[0][j] + bR);
        float zg = sgm(tb[256] + ag[1][j] + bZ);
        float ng = tanh_fast(tb[512] + ag[2][j] + rg * (ag[3][j] + bN));
        float hold = hF[row * HFLD + c];
        float hv = (1.f - zg) * ng + zg * hold;
        hF[row * HFLD + c] = hv;
        u16 hb16 = f2b(hv);
        hB[row * HLD + c] = hb16;
        __builtin_nontemporal_store(hb16,
                                    A.bcat + ((size_t)t * BSZ + r0 + row) * 768 + c);
      }
    }
    __syncthreads();
  }
}

// ---------------- zero t=0 slice -------------------------------------------------
__global__ __launch_bounds__(256) void k_zero0(float* __restrict__ outp) {
  outp[(size_t)blockIdx.x * (TLEN * 256) + threadIdx.x] = 0.f;
}

extern "C" void kernel_launch(void* const* d_in, const int* in_sizes, int n_in,
                              void* d_out, int out_size, void* d_ws, size_t ws_size,
                              hipStream_t stream) {
  (void)in_sizes; (void)n_in; (void)out_size; (void)ws_size;
  const int* src = (const int*)d_in[0];
  const int* trg = (const int*)d_in[1];
  const float* enc_emb = (const float*)d_in[2];
  const float* eWih_f = (const float*)d_in[3];
  const float* eWhh_f = (const float*)d_in[4];
  const float* ebih_f = (const float*)d_in[5];
  const float* ebhh_f = (const float*)d_in[6];
  const float* eWih_b = (const float*)d_in[7];
  const float* eWhh_b = (const float*)d_in[8];
  const float* ebih_b = (const float*)d_in[9];
  const float* ebhh_b = (const float*)d_in[10];
  const float* Wproj = (const float*)d_in[11];
  const float* bproj = (const float*)d_in[12];
  const float* dec_emb = (const float*)d_in[13];
  const float* Wattn = (const float*)d_in[14];
  const float* battn = (const float*)d_in[15];
  const float* v_attn = (const float*)d_in[16];
  const float* dWih = (const float*)d_in[17];
  const float* dWhh = (const float*)d_in[18];
  const float* dbih = (const float*)d_in[19];
  const float* dbhh = (const float*)d_in[20];
  const float* Wfc = (const float*)d_in[21];
  const float* bfc = (const float*)d_in[22];
  float* dout = (float*)d_out;

  char* base = (char*)d_ws;
  size_t off = 0;
  auto alloc = [&](size_t bytes) {
    void* p = base + off;
    off += (bytes + 255) & ~(size_t)255;
    return p;
  };
  u16* enc_b     = (u16*)alloc((size_t)BSZ * SLEN * 512 * 2);
  u16* enc_pre_b = (u16*)alloc((size_t)BSZ * SLEN * 256 * 2);
  u16* bcat      = (u16*)alloc((size_t)31 * BSZ * 768 * 2);
  float* tabf    = (float*)alloc((size_t)64 * 768 * 4);
  float* tabb    = (float*)alloc((size_t)64 * 768 * 4);
  float* tabd    = (float*)alloc((size_t)256 * 768 * 4);
  u16* hcatB     = (u16*)alloc((size_t)BSZ * 512 * 2);
  float* h0f     = (float*)alloc((size_t)BSZ * 256 * 4);
  u16* Whhf_b    = (u16*)alloc((size_t)768 * 256 * 2);
  u16* Whhb_b    = (u16*)alloc((size_t)768 * 256 * 2);
  u16* We_b      = (u16*)alloc((size_t)256 * 512 * 2);
  u16* Wd_b      = (u16*)alloc((size_t)256 * 256 * 2);
  u16* Wproj_b   = (u16*)alloc((size_t)256 * 512 * 2);
  u16* Wg_lo     = (u16*)alloc((size_t)768 * 512 * 2);
  u16* Wg_hi     = (u16*)alloc((size_t)768 * 256 * 2);
  u16* Wfc_b     = (u16*)alloc((size_t)256 * 768 * 2);

  // tables + weight packs
  k_gi_table<<<dim3(64, 3), 256, 0, stream>>>(enc_emb, eWih_f, EDIM, ebih_f, tabf);
  k_gi_table<<<dim3(64, 3), 256, 0, stream>>>(enc_emb, eWih_b, EDIM, ebih_b, tabb);
  k_gi_table<<<dim3(256, 3), 256, 0, stream>>>(dec_emb, dWih, 640, dbih, tabd);
  k_pack<<<dim3(768), 256, 0, stream>>>(Whhf_b, eWhh_f, 256, 0, 256);
  k_pack<<<dim3(768), 256, 0, stream>>>(Whhb_b, eWhh_b, 256, 0, 256);
  k_pack<<<dim3(256), 256, 0, stream>>>(We_b, Wattn, 768, 256, 512);
  k_pack<<<dim3(256), 256, 0, stream>>>(Wd_b, Wattn, 768, 0, 256);
  k_pack<<<dim3(256), 256, 0, stream>>>(Wproj_b, Wproj, 512, 0, 512);
  k_pack<<<dim3(768), 256, 0, stream>>>(Wg_lo, dWih, 640, 128, 512);
  k_pack<<<dim3(768), 256, 0, stream>>>(Wg_hi, dWhh, 256, 0, 256);
  k_pack<<<dim3(256), 256, 0, stream>>>(Wfc_b, Wfc, 768, 0, 768);

  // encoder: persistent, 64 blocks x 1024 threads, zero grid sync
  {
    EncArgs ea{enc_b, hcatB, src, Whhf_b, Whhb_b, ebhh_f, ebhh_b, tabf, tabb};
    k_enc_p<<<dim3(64), dim3(1024), 0, stream>>>(ea);
  }

  // hdec = hcat @ Wproj^T + bproj (fp32 out)
  k_bgemm<false><<<dim3(8, 4), 256, 0, stream>>>(hcatB, 512, Wproj_b, 512, bproj, h0f, 256, 512);
  // enc_pre (bf16) = enc_b @ We^T + battn
  k_bgemm<true><<<dim3(256, 4), 256, 0, stream>>>(enc_b, 512, We_b, 512, battn,
                                                  enc_pre_b, 256, 512);
  k_zero0<<<dim3(BSZ), 256, 0, stream>>>(dout);

  // decoder: persistent, 64 blocks x 1024 threads, zero grid sync
  {
    DecArgs da{enc_b, enc_pre_b, v_attn, Wd_b, Wg_lo, Wg_hi, tabd, dbhh, trg, h0f, bcat};
    k_dec_p<<<dim3(64), dim3(1024), 0, stream>>>(da);
  }

  // deferred logits: [hn|ctx] @ Wfc^T + bfc for all 31 steps at once
  k_bgemm_logits<<<dim3(248, 4), 256, 0, stream>>>(bcat, Wfc_b, bfc, dout);
}

// Round 10
// 2412.445 us; speedup vs baseline: 1.8358x; 1.2207x over previous
//
#include <hip/hip_runtime.h>
#include <math.h>

#define BSZ 1024
#define SLEN 32
#define TLEN 32
#define EDIM 128
#define HLD 264    // u16 row stride for bf16 h in LDS
#define HFLD 260   // f32 row stride
#define CTXLD 520  // u16 row stride for ctx
#define HWLD 260   // f32 row stride for hWd

typedef unsigned short u16;
typedef __attribute__((ext_vector_type(8))) short bf16x8;
typedef __attribute__((ext_vector_type(4))) float f32x4;

__device__ __forceinline__ float sgm(float x) { return 1.0f / (1.0f + __expf(-x)); }
__device__ __forceinline__ float tanh_fast(float x) {
  float e = __expf(-2.0f * fabsf(x));
  float t = (1.0f - e) / (1.0f + e);
  return copysignf(t, x);
}
__device__ __forceinline__ u16 f2b(float f) {
  union { float f; unsigned u; } v; v.f = f;
  unsigned r = v.u + 0x7fffu + ((v.u >> 16) & 1u);
  return (u16)(r >> 16);
}
__device__ __forceinline__ float b2f(u16 h) {
  union { unsigned u; float f; } v; v.u = ((unsigned)h) << 16; return v.f;
}

typedef __attribute__((address_space(1))) const void gv_t;
typedef __attribute__((address_space(3))) void lv_t;
__device__ __forceinline__ void gload16(const void* g, void* l) {
  __builtin_amdgcn_global_load_lds((gv_t*)g, (lv_t*)l, 16, 0, 0);
}

// ---------------- gi tables -------------------------------------------------------
__global__ __launch_bounds__(256) void k_gi_table(const float* __restrict__ emb,
                                                  const float* __restrict__ Wih, int ldw,
                                                  const float* __restrict__ bih,
                                                  float* __restrict__ tab) {
  int v = blockIdx.x;
  int g = blockIdx.y * 256 + threadIdx.x;
  __shared__ float e[EDIM];
  if (threadIdx.x < EDIM) e[threadIdx.x] = emb[v * EDIM + threadIdx.x];
  __syncthreads();
  const float4* w4 = (const float4*)(Wih + (size_t)g * ldw);
  float acc = 0.f;
#pragma unroll
  for (int j = 0; j < EDIM / 4; ++j) {
    float4 w = w4[j];
    acc += w.x * e[4 * j] + w.y * e[4 * j + 1] + w.z * e[4 * j + 2] + w.w * e[4 * j + 3];
  }
  tab[(size_t)v * 768 + g] = acc + bih[g];
}

// ---------------- fp32 -> bf16 weight pack ---------------------------------------
__global__ __launch_bounds__(256) void k_pack(u16* __restrict__ dst,
                                              const float* __restrict__ src, int ld,
                                              int off, int n) {
  int r = blockIdx.x;
  for (int c = threadIdx.x; c < n; c += 256)
    dst[(size_t)r * n + c] = f2b(src[(size_t)r * ld + off + c]);
}

// ---------------- bf16 MFMA GEMM 128x64: out = A.B^T + bias ----------------------
template <bool B16OUT>
__global__ __launch_bounds__(256) void k_bgemm(const u16* __restrict__ A, int lda,
                                               const u16* __restrict__ B, int ldb,
                                               const float* __restrict__ bias,
                                               void* __restrict__ outv, int ldo, int K) {
  __shared__ u16 sA[128 * 64];
  __shared__ u16 sB[64 * 64];
  int m0 = blockIdx.x * 128, n0 = blockIdx.y * 64;
  int tid = threadIdx.x, w = tid >> 6, l = tid & 63;
  int wr = w >> 1, wc = w & 1;
  f32x4 acc[4][2] = {};
  for (int k0 = 0; k0 < K; k0 += 64) {
    __syncthreads();
#pragma unroll
    for (int i = 0; i < 4; ++i) {
      int chunk = i * 4 + w;
      int d = chunk * 1024 + l * 16;
      int lg = d ^ (((d >> 7) & 7) << 4);
      int row = lg >> 7, kb = lg & 127;
      gload16((const char*)(A + (size_t)(m0 + row) * lda + k0) + kb, (char*)sA + chunk * 1024);
    }
#pragma unroll
    for (int i = 0; i < 2; ++i) {
      int chunk = i * 4 + w;
      int d = chunk * 1024 + l * 16;
      int lg = d ^ (((d >> 7) & 7) << 4);
      int row = lg >> 7, kb = lg & 127;
      gload16((const char*)(B + (size_t)(n0 + row) * ldb + k0) + kb, (char*)sB + chunk * 1024);
    }
    __syncthreads();
#pragma unroll
    for (int kk = 0; kk < 2; ++kk) {
      bf16x8 av[4], bv[2];
#pragma unroll
      for (int fm = 0; fm < 4; ++fm) {
        int row = wr * 64 + fm * 16 + (l & 15);
        int addr = (row * 128 + kk * 64 + (l >> 4) * 16) ^ ((row & 7) << 4);
        av[fm] = *(const bf16x8*)((const char*)sA + addr);
      }
#pragma unroll
      for (int fn = 0; fn < 2; ++fn) {
        int row = wc * 32 + fn * 16 + (l & 15);
        int addr = (row * 128 + kk * 64 + (l >> 4) * 16) ^ ((row & 7) << 4);
        bv[fn] = *(const bf16x8*)((const char*)sB + addr);
      }
#pragma unroll
      for (int fm = 0; fm < 4; ++fm)
#pragma unroll
        for (int fn = 0; fn < 2; ++fn)
          acc[fm][fn] = __builtin_amdgcn_mfma_f32_16x16x32_bf16(av[fm], bv[fn], acc[fm][fn], 0, 0, 0);
    }
  }
#pragma unroll
  for (int fn = 0; fn < 2; ++fn) {
    int c = n0 + wc * 32 + fn * 16 + (l & 15);
    float bb = bias ? bias[c] : 0.f;
#pragma unroll
    for (int fm = 0; fm < 4; ++fm) {
      int r = m0 + wr * 64 + fm * 16 + (l >> 4) * 4;
#pragma unroll
      for (int j = 0; j < 4; ++j) {
        float val = acc[fm][fn][j] + bb;
        if (B16OUT) ((u16*)outv)[(size_t)(r + j) * ldo + c] = f2b(val);
        else        ((float*)outv)[(size_t)(r + j) * ldo + c] = val;
      }
    }
  }
}

// ---------------- batched logits GEMM: bcat(31744x768) @ Wfc^T -> dout scatter ----
__global__ __launch_bounds__(256) void k_bgemm_logits(const u16* __restrict__ A,
                                                      const u16* __restrict__ B,
                                                      const float* __restrict__ bias,
                                                      float* __restrict__ dout) {
  __shared__ u16 sA[128 * 64];
  __shared__ u16 sB[64 * 64];
  int m0 = blockIdx.x * 128, n0 = blockIdx.y * 64;
  int tid = threadIdx.x, w = tid >> 6, l = tid & 63;
  int wr = w >> 1, wc = w & 1;
  f32x4 acc[4][2] = {};
  for (int k0 = 0; k0 < 768; k0 += 64) {
    __syncthreads();
#pragma unroll
    for (int i = 0; i < 4; ++i) {
      int chunk = i * 4 + w;
      int d = chunk * 1024 + l * 16;
      int lg = d ^ (((d >> 7) & 7) << 4);
      int row = lg >> 7, kb = lg & 127;
      gload16((const char*)(A + (size_t)(m0 + row) * 768 + k0) + kb, (char*)sA + chunk * 1024);
    }
#pragma unroll
    for (int i = 0; i < 2; ++i) {
      int chunk = i * 4 + w;
      int d = chunk * 1024 + l * 16;
      int lg = d ^ (((d >> 7) & 7) << 4);
      int row = lg >> 7, kb = lg & 127;
      gload16((const char*)(B + (size_t)(n0 + row) * 768 + k0) + kb, (char*)sB + chunk * 1024);
    }
    __syncthreads();
#pragma unroll
    for (int kk = 0; kk < 2; ++kk) {
      bf16x8 av[4], bv[2];
#pragma unroll
      for (int fm = 0; fm < 4; ++fm) {
        int row = wr * 64 + fm * 16 + (l & 15);
        int addr = (row * 128 + kk * 64 + (l >> 4) * 16) ^ ((row & 7) << 4);
        av[fm] = *(const bf16x8*)((const char*)sA + addr);
      }
#pragma unroll
      for (int fn = 0; fn < 2; ++fn) {
        int row = wc * 32 + fn * 16 + (l & 15);
        int addr = (row * 128 + kk * 64 + (l >> 4) * 16) ^ ((row & 7) << 4);
        bv[fn] = *(const bf16x8*)((const char*)sB + addr);
      }
#pragma unroll
      for (int fm = 0; fm < 4; ++fm)
#pragma unroll
        for (int fn = 0; fn < 2; ++fn)
          acc[fm][fn] = __builtin_amdgcn_mfma_f32_16x16x32_bf16(av[fm], bv[fn], acc[fm][fn], 0, 0, 0);
    }
  }
#pragma unroll
  for (int fn = 0; fn < 2; ++fn) {
    int c = n0 + wc * 32 + fn * 16 + (l & 15);
    float bb = bias[c];
#pragma unroll
    for (int fm = 0; fm < 4; ++fm) {
#pragma unroll
      for (int j = 0; j < 4; ++j) {
        int gr = m0 + wr * 64 + fm * 16 + (l >> 4) * 4 + j;
        int tt = gr >> 10, b = gr & 1023;
        dout[(size_t)b * (TLEN * 256) + (size_t)(tt + 1) * 256 + c] = acc[fm][fn][j] + bb;
      }
    }
  }
}

// ---------------- persistent encoder: 256 blocks x 4 rows, 16 waves --------------
struct EncArgs {
  u16* enc_b; u16* hcatB; const int* src;
  const u16* Whhf; const u16* Whhb;
  const float* bhhf; const float* bhhb;
  const float* tabf; const float* tabb;
};

__global__ __launch_bounds__(1024) void k_enc_p(EncArgs E) {
  __shared__ float hF[2][4 * HFLD];
  __shared__ u16 hB[2][16 * HLD];
  __shared__ int toks[128];
  int r0 = blockIdx.x * 4;
  int tid = threadIdx.x, w = tid >> 6, l = tid & 63;
  int dir = w >> 3, wc = w & 7;  // wave: direction + 32-col slice
  for (int i = tid; i < 16 * HLD; i += 1024) { hB[0][i] = 0; hB[1][i] = 0; }
  __syncthreads();
  if (tid < 1024) {
    int r = tid >> 8, c = tid & 255;
    hF[0][r * HFLD + c] = 0.f; hF[1][r * HFLD + c] = 0.f;
  }
  if (tid < 128) toks[tid] = E.src[(size_t)(r0 + (tid >> 5)) * SLEN + (tid & 31)];
  __syncthreads();
  const u16* Whh = dir ? E.Whhb : E.Whhf;
  const float* tab = dir ? E.tabb : E.tabf;
  const float* bhh = dir ? E.bhhb : E.bhhf;
  for (int s = 0; s < SLEN; ++s) {
    int s_store = dir ? (SLEN - 1 - s) : s;
    f32x4 ae[3][2] = {};
    if (s > 0) {
      bf16x8 pw[3][3][2];
#pragma unroll
      for (int r = 0; r < 3; ++r)
#pragma unroll
        for (int g = 0; g < 3; ++g)
#pragma unroll
          for (int fn = 0; fn < 2; ++fn)
            pw[r][g][fn] = *(const bf16x8*)(Whh +
                (size_t)(g * 256 + wc * 32 + fn * 16 + (l & 15)) * 256 + r * 32 + (l >> 4) * 8);
#pragma unroll
      for (int kk = 0; kk < 8; ++kk) {
        int slot = kk % 3;
        bf16x8 av = *(const bf16x8*)(hB[dir] + (l & 15) * HLD + kk * 32 + (l >> 4) * 8);
#pragma unroll
        for (int g = 0; g < 3; ++g)
#pragma unroll
          for (int fn = 0; fn < 2; ++fn)
            ae[g][fn] = __builtin_amdgcn_mfma_f32_16x16x32_bf16(av, pw[slot][g][fn], ae[g][fn], 0, 0, 0);
        if (kk + 3 < 8) {
#pragma unroll
          for (int g = 0; g < 3; ++g)
#pragma unroll
            for (int fn = 0; fn < 2; ++fn)
              pw[slot][g][fn] = *(const bf16x8*)(Whh +
                  (size_t)(g * 256 + wc * 32 + fn * 16 + (l & 15)) * 256 + (kk + 3) * 32 + (l >> 4) * 8);
        }
      }
    }
    __syncthreads();
#pragma unroll
    for (int fn = 0; fn < 2; ++fn) {
      int c = wc * 32 + fn * 16 + (l & 15);
      float bR = bhh[c], bZ = bhh[256 + c], bN = bhh[512 + c];
#pragma unroll
      for (int j = 0; j < 4; ++j) {
        int row = (l >> 4) * 4 + j;
        if (row < 4) {
          const float* tb = tab + (size_t)toks[row * 32 + s_store] * 768 + c;
          float rg = sgm(tb[0] + ae[0][fn][j] + bR);
          float zg = sgm(tb[256] + ae[1][fn][j] + bZ);
          float ng = tanh_fast(tb[512] + rg * (ae[2][fn][j] + bN));
          float hold = hF[dir][row * HFLD + c];
          float hv = (1.f - zg) * ng + zg * hold;
          hF[dir][row * HFLD + c] = hv;
          u16 hb16 = f2b(hv);
          hB[dir][row * HLD + c] = hb16;
          __builtin_nontemporal_store(
              hb16, E.enc_b + ((size_t)(r0 + row) * SLEN + s_store) * 512 + dir * 256 + c);
        }
      }
    }
    __syncthreads();
  }
  for (int i = tid; i < 4 * 512; i += 1024) {
    int r = i >> 9, c = i & 511;
    E.hcatB[(size_t)(r0 + r) * 512 + c] =
        (c < 256) ? hB[0][r * HLD + c] : hB[1][r * HLD + (c - 256)];
  }
}

// ---------------- persistent decoder: 256 blocks x 4 rows, 16 waves --------------
struct DecArgs {
  const u16* enc_b; const u16* enc_pre_b; const float* v_attn;
  const u16* Wd_b; const u16* Wg_lo; const u16* Wg_hi;
  const float* tabd; const float* dbhh;
  const int* trg; const float* h0f;
  u16* bcat;
};

__global__ __launch_bounds__(1024) void k_dec_p(DecArgs A) {
  __shared__ float hF[4 * HFLD];
  __shared__ u16 hB[16 * HLD];
  __shared__ u16 ctxB[16 * CTXLD];
  __shared__ float hwS[4 * HWLD];
  __shared__ float awS[4 * 33];
  __shared__ float scS[4 * 32];
  __shared__ float vS[256];
  __shared__ int toks[128];
  int r0 = blockIdx.x * 4;
  int tid = threadIdx.x, w = tid >> 6, l = tid & 63;
  for (int i = tid; i < 16 * HLD; i += 1024) hB[i] = 0;
  for (int i = tid; i < 16 * CTXLD; i += 1024) ctxB[i] = 0;
  __syncthreads();
  {
    int r = tid >> 8, c = tid & 255;
    float v = A.h0f[(size_t)(r0 + r) * 256 + c];
    hF[r * HFLD + c] = v;
    hB[r * HLD + c] = f2b(v);
  }
  if (tid < 256) vS[tid] = A.v_attn[tid];
  if (tid < 128) toks[tid] = A.trg[(size_t)(r0 + (tid >> 5)) * TLEN + (tid & 31)];
  __syncthreads();
  for (int t = 0; t < TLEN - 1; ++t) {
    // ---- P1: hWd = h @ Wd^T : wave w -> cols [w*16, w*16+16), depth-4 ring ----
    {
      f32x4 a1 = {};
      bf16x8 pw[4];
#pragma unroll
      for (int r = 0; r < 4; ++r)
        pw[r] = *(const bf16x8*)(A.Wd_b + (size_t)(w * 16 + (l & 15)) * 256 + r * 32 + (l >> 4) * 8);
#pragma unroll
      for (int kk = 0; kk < 8; ++kk) {
        int slot = kk % 4;
        bf16x8 av = *(const bf16x8*)(hB + (l & 15) * HLD + kk * 32 + (l >> 4) * 8);
        a1 = __builtin_amdgcn_mfma_f32_16x16x32_bf16(av, pw[slot], a1, 0, 0, 0);
        if (kk + 4 < 8)
          pw[slot] = *(const bf16x8*)(A.Wd_b + (size_t)(w * 16 + (l & 15)) * 256 + (kk + 4) * 32 + (l >> 4) * 8);
      }
      int c = w * 16 + (l & 15);
#pragma unroll
      for (int j = 0; j < 4; ++j) {
        int row = (l >> 4) * 4 + j;
        if (row < 4) hwS[row * HWLD + c] = a1[j];
      }
    }
    __syncthreads();
    // ---- P2: scores: (r = tid>>8, s = (tid>>3)&31, part = tid&7) ----
    {
      int r = tid >> 8, s = (tid >> 3) & 31, part = tid & 7;
      const u16* ep = A.enc_pre_b + ((size_t)(r0 + r) * SLEN + s) * 256 + part * 32;
      const float* hw = hwS + r * HWLD + part * 32;
      const float* vv = vS + part * 32;
      float sum = 0.f;
#pragma unroll
      for (int a0 = 0; a0 < 32; a0 += 8) {
        bf16x8 pk = *(const bf16x8*)(ep + a0);
#pragma unroll
        for (int q = 0; q < 8; ++q)
          sum += vv[a0 + q] * tanh_fast(b2f((u16)pk[q]) + hw[a0 + q]);
      }
      sum += __shfl_xor(sum, 1);
      sum += __shfl_xor(sum, 2);
      sum += __shfl_xor(sum, 4);
      if (part == 0) scS[r * 32 + s] = sum;
    }
    __syncthreads();
    // softmax over s: tid<128, r = tid>>5, s = tid&31 (lanes 0-31 / 32-63 halves)
    if (tid < 128) {
      int r = tid >> 5, s = tid & 31;
      float v = scS[r * 32 + s], m = v;
#pragma unroll
      for (int o = 1; o <= 16; o <<= 1) m = fmaxf(m, __shfl_xor(m, o));
      float e = __expf(v - m), ss = e;
#pragma unroll
      for (int o = 1; o <= 16; o <<= 1) ss += __shfl_xor(ss, o);
      awS[r * 33 + s] = e / ss;
    }
    __syncthreads();
    // ---- P3: ctx: (r = tid>>8, c8 = (tid>>2)&63, sp = tid&3) ----
    {
      int r = tid >> 8, c = ((tid >> 2) & 63) * 8, sp = tid & 3;
      float a8[8] = {};
      const u16* eb = A.enc_b + ((size_t)(r0 + r) * SLEN + sp * 8) * 512 + c;
#pragma unroll
      for (int s2 = 0; s2 < 8; ++s2) {
        float a = awS[r * 33 + sp * 8 + s2];
        bf16x8 pk = *(const bf16x8*)(eb + s2 * 512);
#pragma unroll
        for (int q = 0; q < 8; ++q) a8[q] += a * b2f((u16)pk[q]);
      }
#pragma unroll
      for (int o = 1; o <= 2; o <<= 1)
#pragma unroll
        for (int q = 0; q < 8; ++q) a8[q] += __shfl_xor(a8[q], o);
      if (sp == 0) {
        bf16x8 o;
#pragma unroll
        for (int q = 0; q < 8; ++q) o[q] = (short)f2b(a8[q]);
        *(bf16x8*)(ctxB + r * CTXLD + c) = o;
        __builtin_nontemporal_store(
            o, (bf16x8*)(A.bcat + ((size_t)t * BSZ + r0 + r) * 768 + 256 + c));
      }
    }
    __syncthreads();
    // ---- P4: gates, depth-6 register ring over 24 k-iters ----
    f32x4 ag[4] = {};
    {
      bf16x8 pf[6][3];
#pragma unroll
      for (int r = 0; r < 6; ++r)
#pragma unroll
        for (int gb = 0; gb < 3; ++gb)
          pf[r][gb] = *(const bf16x8*)(A.Wg_lo +
              (size_t)(gb * 256 + w * 16 + (l & 15)) * 512 + r * 32 + (l >> 4) * 8);
#pragma unroll
      for (int kk = 0; kk < 24; ++kk) {
        int slot = kk % 6;
        bf16x8 av = (kk < 16)
            ? *(const bf16x8*)(ctxB + (l & 15) * CTXLD + kk * 32 + (l >> 4) * 8)
            : *(const bf16x8*)(hB + (l & 15) * HLD + (kk - 16) * 32 + (l >> 4) * 8);
#pragma unroll
        for (int gb = 0; gb < 3; ++gb) {
          int ai = (kk < 16) ? gb : (gb == 2 ? 3 : gb);
          ag[ai] = __builtin_amdgcn_mfma_f32_16x16x32_bf16(av, pf[slot][gb], ag[ai], 0, 0, 0);
        }
        int kn = kk + 6;
        if (kn < 24) {
#pragma unroll
          for (int gb = 0; gb < 3; ++gb) {
            if (kn < 16)
              pf[slot][gb] = *(const bf16x8*)(A.Wg_lo +
                  (size_t)(gb * 256 + w * 16 + (l & 15)) * 512 + kn * 32 + (l >> 4) * 8);
            else
              pf[slot][gb] = *(const bf16x8*)(A.Wg_hi +
                  (size_t)(gb * 256 + w * 16 + (l & 15)) * 256 + (kn - 16) * 32 + (l >> 4) * 8);
          }
        }
      }
    }
    __syncthreads();
    // ---- P5: GRU epilogue: wave w -> col c = w*16 + (l&15), rows < 4 ----
    {
      int c = w * 16 + (l & 15);
      float bR = A.dbhh[c], bZ = A.dbhh[256 + c], bN = A.dbhh[512 + c];
#pragma unroll
      for (int j = 0; j < 4; ++j) {
        int row = (l >> 4) * 4 + j;
        if (row < 4) {
          const float* tb = A.tabd + (size_t)toks[row * 32 + t] * 768 + c;
          float rg = sgm(tb[0] + ag[0][j] + bR);
          float zg = sgm(tb[256] + ag[1][j] + bZ);
          float ng = tanh_fast(tb[512] + ag[2][j] + rg * (ag[3][j] + bN));
          float hold = hF[row * HFLD + c];
          float hv = (1.f - zg) * ng + zg * hold;
          hF[row * HFLD + c] = hv;
          u16 hb16 = f2b(hv);
          hB[row * HLD + c] = hb16;
          __builtin_nontemporal_store(hb16,
                                      A.bcat + ((size_t)t * BSZ + r0 + row) * 768 + c);
        }
      }
    }
    __syncthreads();
  }
}

// ---------------- zero t=0 slice -------------------------------------------------
__global__ __launch_bounds__(256) void k_zero0(float* __restrict__ outp) {
  outp[(size_t)blockIdx.x * (TLEN * 256) + threadIdx.x] = 0.f;
}

extern "C" void kernel_launch(void* const* d_in, const int* in_sizes, int n_in,
                              void* d_out, int out_size, void* d_ws, size_t ws_size,
                              hipStream_t stream) {
  (void)in_sizes; (void)n_in; (void)out_size; (void)ws_size;
  const int* src = (const int*)d_in[0];
  const int* trg = (const int*)d_in[1];
  const float* enc_emb = (const float*)d_in[2];
  const float* eWih_f = (const float*)d_in[3];
  const float* eWhh_f = (const float*)d_in[4];
  const float* ebih_f = (const float*)d_in[5];
  const float* ebhh_f = (const float*)d_in[6];
  const float* eWih_b = (const float*)d_in[7];
  const float* eWhh_b = (const float*)d_in[8];
  const float* ebih_b = (const float*)d_in[9];
  const float* ebhh_b = (const float*)d_in[10];
  const float* Wproj = (const float*)d_in[11];
  const float* bproj = (const float*)d_in[12];
  const float* dec_emb = (const float*)d_in[13];
  const float* Wattn = (const float*)d_in[14];
  const float* battn = (const float*)d_in[15];
  const float* v_attn = (const float*)d_in[16];
  const float* dWih = (const float*)d_in[17];
  const float* dWhh = (const float*)d_in[18];
  const float* dbih = (const float*)d_in[19];
  const float* dbhh = (const float*)d_in[20];
  const float* Wfc = (const float*)d_in[21];
  const float* bfc = (const float*)d_in[22];
  float* dout = (float*)d_out;

  char* base = (char*)d_ws;
  size_t off = 0;
  auto alloc = [&](size_t bytes) {
    void* p = base + off;
    off += (bytes + 255) & ~(size_t)255;
    return p;
  };
  u16* enc_b     = (u16*)alloc((size_t)BSZ * SLEN * 512 * 2);
  u16* enc_pre_b = (u16*)alloc((size_t)BSZ * SLEN * 256 * 2);
  u16* bcat      = (u16*)alloc((size_t)31 * BSZ * 768 * 2);
  float* tabf    = (float*)alloc((size_t)64 * 768 * 4);
  float* tabb    = (float*)alloc((size_t)64 * 768 * 4);
  float* tabd    = (float*)alloc((size_t)256 * 768 * 4);
  u16* hcatB     = (u16*)alloc((size_t)BSZ * 512 * 2);
  float* h0f     = (float*)alloc((size_t)BSZ * 256 * 4);
  u16* Whhf_b    = (u16*)alloc((size_t)768 * 256 * 2);
  u16* Whhb_b    = (u16*)alloc((size_t)768 * 256 * 2);
  u16* We_b      = (u16*)alloc((size_t)256 * 512 * 2);
  u16* Wd_b      = (u16*)alloc((size_t)256 * 256 * 2);
  u16* Wproj_b   = (u16*)alloc((size_t)256 * 512 * 2);
  u16* Wg_lo     = (u16*)alloc((size_t)768 * 512 * 2);
  u16* Wg_hi     = (u16*)alloc((size_t)768 * 256 * 2);
  u16* Wfc_b     = (u16*)alloc((size_t)256 * 768 * 2);

  // tables + weight packs
  k_gi_table<<<dim3(64, 3), 256, 0, stream>>>(enc_emb, eWih_f, EDIM, ebih_f, tabf);
  k_gi_table<<<dim3(64, 3), 256, 0, stream>>>(enc_emb, eWih_b, EDIM, ebih_b, tabb);
  k_gi_table<<<dim3(256, 3), 256, 0, stream>>>(dec_emb, dWih, 640, dbih, tabd);
  k_pack<<<dim3(768), 256, 0, stream>>>(Whhf_b, eWhh_f, 256, 0, 256);
  k_pack<<<dim3(768), 256, 0, stream>>>(Whhb_b, eWhh_b, 256, 0, 256);
  k_pack<<<dim3(256), 256, 0, stream>>>(We_b, Wattn, 768, 256, 512);
  k_pack<<<dim3(256), 256, 0, stream>>>(Wd_b, Wattn, 768, 0, 256);
  k_pack<<<dim3(256), 256, 0, stream>>>(Wproj_b, Wproj, 512, 0, 512);
  k_pack<<<dim3(768), 256, 0, stream>>>(Wg_lo, dWih, 640, 128, 512);
  k_pack<<<dim3(768), 256, 0, stream>>>(Wg_hi, dWhh, 256, 0, 256);
  k_pack<<<dim3(256), 256, 0, stream>>>(Wfc_b, Wfc, 768, 0, 768);

  // encoder: persistent, 256 blocks x 4 rows, zero grid sync
  {
    EncArgs ea{enc_b, hcatB, src, Whhf_b, Whhb_b, ebhh_f, ebhh_b, tabf, tabb};
    k_enc_p<<<dim3(256), dim3(1024), 0, stream>>>(ea);
  }

  // hdec = hcat @ Wproj^T + bproj (fp32 out)
  k_bgemm<false><<<dim3(8, 4), 256, 0, stream>>>(hcatB, 512, Wproj_b, 512, bproj, h0f, 256, 512);
  // enc_pre (bf16) = enc_b @ We^T + battn
  k_bgemm<true><<<dim3(256, 4), 256, 0, stream>>>(enc_b, 512, We_b, 512, battn,
                                                  enc_pre_b, 256, 512);
  k_zero0<<<dim3(BSZ), 256, 0, stream>>>(dout);

  // decoder: persistent, 256 blocks x 4 rows, zero grid sync
  {
    DecArgs da{enc_b, enc_pre_b, v_attn, Wd_b, Wg_lo, Wg_hi, tabd, dbhh, trg, h0f, bcat};
    k_dec_p<<<dim3(256), dim3(1024), 0, stream>>>(da);
  }

  // deferred logits: [hn|ctx] @ Wfc^T + bfc for all 31 steps at once
  k_bgemm_logits<<<dim3(248, 4), 256, 0, stream>>>(bcat, Wfc_b, bfc, dout);
}

// Round 11
// 2310.337 us; speedup vs baseline: 1.9169x; 1.0442x over previous
//
#include <hip/hip_runtime.h>
#include <math.h>

#define BSZ 1024
#define SLEN 32
#define TLEN 32
#define EDIM 128
#define HLD 264    // u16 row stride for bf16 h in LDS
#define HFLD 260   // f32 row stride
#define CTXLD 520  // u16 row stride for ctx
#define HWLD 260   // f32 row stride for hWd

typedef unsigned short u16;
typedef __attribute__((ext_vector_type(8))) short bf16x8;
typedef __attribute__((ext_vector_type(4))) float f32x4;

__device__ __forceinline__ float sgm(float x) { return 1.0f / (1.0f + __expf(-x)); }
__device__ __forceinline__ float tanh_fast(float x) {
  float e = __expf(-2.0f * fabsf(x));
  float t = (1.0f - e) / (1.0f + e);
  return copysignf(t, x);
}
__device__ __forceinline__ u16 f2b(float f) {
  union { float f; unsigned u; } v; v.f = f;
  unsigned r = v.u + 0x7fffu + ((v.u >> 16) & 1u);
  return (u16)(r >> 16);
}
__device__ __forceinline__ float b2f(u16 h) {
  union { unsigned u; float f; } v; v.u = ((unsigned)h) << 16; return v.f;
}

typedef __attribute__((address_space(1))) const void gv_t;
typedef __attribute__((address_space(3))) void lv_t;
__device__ __forceinline__ void gload16(const void* g, void* l) {
  __builtin_amdgcn_global_load_lds((gv_t*)g, (lv_t*)l, 16, 0, 0);
}

// ---------------- gi tables -------------------------------------------------------
__global__ __launch_bounds__(256) void k_gi_table(const float* __restrict__ emb,
                                                  const float* __restrict__ Wih, int ldw,
                                                  const float* __restrict__ bih,
                                                  float* __restrict__ tab) {
  int v = blockIdx.x;
  int g = blockIdx.y * 256 + threadIdx.x;
  __shared__ float e[EDIM];
  if (threadIdx.x < EDIM) e[threadIdx.x] = emb[v * EDIM + threadIdx.x];
  __syncthreads();
  const float4* w4 = (const float4*)(Wih + (size_t)g * ldw);
  float acc = 0.f;
#pragma unroll
  for (int j = 0; j < EDIM / 4; ++j) {
    float4 w = w4[j];
    acc += w.x * e[4 * j] + w.y * e[4 * j + 1] + w.z * e[4 * j + 2] + w.w * e[4 * j + 3];
  }
  tab[(size_t)v * 768 + g] = acc + bih[g];
}

// ---------------- fp32 -> bf16 weight pack ---------------------------------------
__global__ __launch_bounds__(256) void k_pack(u16* __restrict__ dst,
                                              const float* __restrict__ src, int ld,
                                              int off, int n) {
  int r = blockIdx.x;
  for (int c = threadIdx.x; c < n; c += 256)
    dst[(size_t)r * n + c] = f2b(src[(size_t)r * ld + off + c]);
}

// ---------------- bf16 MFMA GEMM 128x64: out = A.B^T + bias ----------------------
template <bool B16OUT>
__global__ __launch_bounds__(256) void k_bgemm(const u16* __restrict__ A, int lda,
                                               const u16* __restrict__ B, int ldb,
                                               const float* __restrict__ bias,
                                               void* __restrict__ outv, int ldo, int K) {
  __shared__ u16 sA[128 * 64];
  __shared__ u16 sB[64 * 64];
  int m0 = blockIdx.x * 128, n0 = blockIdx.y * 64;
  int tid = threadIdx.x, w = tid >> 6, l = tid & 63;
  int wr = w >> 1, wc = w & 1;
  f32x4 acc[4][2] = {};
  for (int k0 = 0; k0 < K; k0 += 64) {
    __syncthreads();
#pragma unroll
    for (int i = 0; i < 4; ++i) {
      int chunk = i * 4 + w;
      int d = chunk * 1024 + l * 16;
      int lg = d ^ (((d >> 7) & 7) << 4);
      int row = lg >> 7, kb = lg & 127;
      gload16((const char*)(A + (size_t)(m0 + row) * lda + k0) + kb, (char*)sA + chunk * 1024);
    }
#pragma unroll
    for (int i = 0; i < 2; ++i) {
      int chunk = i * 4 + w;
      int d = chunk * 1024 + l * 16;
      int lg = d ^ (((d >> 7) & 7) << 4);
      int row = lg >> 7, kb = lg & 127;
      gload16((const char*)(B + (size_t)(n0 + row) * ldb + k0) + kb, (char*)sB + chunk * 1024);
    }
    __syncthreads();
#pragma unroll
    for (int kk = 0; kk < 2; ++kk) {
      bf16x8 av[4], bv[2];
#pragma unroll
      for (int fm = 0; fm < 4; ++fm) {
        int row = wr * 64 + fm * 16 + (l & 15);
        int addr = (row * 128 + kk * 64 + (l >> 4) * 16) ^ ((row & 7) << 4);
        av[fm] = *(const bf16x8*)((const char*)sA + addr);
      }
#pragma unroll
      for (int fn = 0; fn < 2; ++fn) {
        int row = wc * 32 + fn * 16 + (l & 15);
        int addr = (row * 128 + kk * 64 + (l >> 4) * 16) ^ ((row & 7) << 4);
        bv[fn] = *(const bf16x8*)((const char*)sB + addr);
      }
#pragma unroll
      for (int fm = 0; fm < 4; ++fm)
#pragma unroll
        for (int fn = 0; fn < 2; ++fn)
          acc[fm][fn] = __builtin_amdgcn_mfma_f32_16x16x32_bf16(av[fm], bv[fn], acc[fm][fn], 0, 0, 0);
    }
  }
#pragma unroll
  for (int fn = 0; fn < 2; ++fn) {
    int c = n0 + wc * 32 + fn * 16 + (l & 15);
    float bb = bias ? bias[c] : 0.f;
#pragma unroll
    for (int fm = 0; fm < 4; ++fm) {
      int r = m0 + wr * 64 + fm * 16 + (l >> 4) * 4;
#pragma unroll
      for (int j = 0; j < 4; ++j) {
        float val = acc[fm][fn][j] + bb;
        if (B16OUT) ((u16*)outv)[(size_t)(r + j) * ldo + c] = f2b(val);
        else        ((float*)outv)[(size_t)(r + j) * ldo + c] = val;
      }
    }
  }
}

// ---------------- batched logits GEMM: bcat(31744x768) @ Wfc^T -> dout scatter ----
__global__ __launch_bounds__(256) void k_bgemm_logits(const u16* __restrict__ A,
                                                      const u16* __restrict__ B,
                                                      const float* __restrict__ bias,
                                                      float* __restrict__ dout) {
  __shared__ u16 sA[128 * 64];
  __shared__ u16 sB[64 * 64];
  int m0 = blockIdx.x * 128, n0 = blockIdx.y * 64;
  int tid = threadIdx.x, w = tid >> 6, l = tid & 63;
  int wr = w >> 1, wc = w & 1;
  f32x4 acc[4][2] = {};
  for (int k0 = 0; k0 < 768; k0 += 64) {
    __syncthreads();
#pragma unroll
    for (int i = 0; i < 4; ++i) {
      int chunk = i * 4 + w;
      int d = chunk * 1024 + l * 16;
      int lg = d ^ (((d >> 7) & 7) << 4);
      int row = lg >> 7, kb = lg & 127;
      gload16((const char*)(A + (size_t)(m0 + row) * 768 + k0) + kb, (char*)sA + chunk * 1024);
    }
#pragma unroll
    for (int i = 0; i < 2; ++i) {
      int chunk = i * 4 + w;
      int d = chunk * 1024 + l * 16;
      int lg = d ^ (((d >> 7) & 7) << 4);
      int row = lg >> 7, kb = lg & 127;
      gload16((const char*)(B + (size_t)(n0 + row) * 768 + k0) + kb, (char*)sB + chunk * 1024);
    }
    __syncthreads();
#pragma unroll
    for (int kk = 0; kk < 2; ++kk) {
      bf16x8 av[4], bv[2];
#pragma unroll
      for (int fm = 0; fm < 4; ++fm) {
        int row = wr * 64 + fm * 16 + (l & 15);
        int addr = (row * 128 + kk * 64 + (l >> 4) * 16) ^ ((row & 7) << 4);
        av[fm] = *(const bf16x8*)((const char*)sA + addr);
      }
#pragma unroll
      for (int fn = 0; fn < 2; ++fn) {
        int row = wc * 32 + fn * 16 + (l & 15);
        int addr = (row * 128 + kk * 64 + (l >> 4) * 16) ^ ((row & 7) << 4);
        bv[fn] = *(const bf16x8*)((const char*)sB + addr);
      }
#pragma unroll
      for (int fm = 0; fm < 4; ++fm)
#pragma unroll
        for (int fn = 0; fn < 2; ++fn)
          acc[fm][fn] = __builtin_amdgcn_mfma_f32_16x16x32_bf16(av[fm], bv[fn], acc[fm][fn], 0, 0, 0);
    }
  }
#pragma unroll
  for (int fn = 0; fn < 2; ++fn) {
    int c = n0 + wc * 32 + fn * 16 + (l & 15);
    float bb = bias[c];
#pragma unroll
    for (int fm = 0; fm < 4; ++fm) {
#pragma unroll
      for (int j = 0; j < 4; ++j) {
        int gr = m0 + wr * 64 + fm * 16 + (l >> 4) * 4 + j;
        int tt = gr >> 10, b = gr & 1023;
        dout[(size_t)b * (TLEN * 256) + (size_t)(tt + 1) * 256 + c] = acc[fm][fn][j] + bb;
      }
    }
  }
}

// ---------------- persistent encoder: 256 blocks x 4 rows, 16 waves --------------
struct EncArgs {
  u16* enc_b; u16* hcatB; const int* src;
  const u16* Whhf; const u16* Whhb;
  const float* bhhf; const float* bhhb;
  const float* tabf; const float* tabb;
};

__global__ __launch_bounds__(1024) void k_enc_p(EncArgs E) {
  __shared__ float hF[2][4 * HFLD];
  __shared__ u16 hB[2][16 * HLD];
  __shared__ int toks[128];
  int r0 = blockIdx.x * 4;
  int tid = threadIdx.x, w = tid >> 6, l = tid & 63;
  int dir = w >> 3, wc = w & 7;  // wave: direction + 32-col slice
  for (int i = tid; i < 16 * HLD; i += 1024) { hB[0][i] = 0; hB[1][i] = 0; }
  __syncthreads();
  if (tid < 1024) {
    int r = tid >> 8, c = tid & 255;
    hF[0][r * HFLD + c] = 0.f; hF[1][r * HFLD + c] = 0.f;
  }
  if (tid < 128) toks[tid] = E.src[(size_t)(r0 + (tid >> 5)) * SLEN + (tid & 31)];
  __syncthreads();
  const u16* Whh = dir ? E.Whhb : E.Whhf;
  const float* tab = dir ? E.tabb : E.tabf;
  const float* bhh = dir ? E.bhhb : E.bhhf;
  for (int s = 0; s < SLEN; ++s) {
    int s_store = dir ? (SLEN - 1 - s) : s;
    f32x4 ae[3][2] = {};
    if (s > 0) {
      bf16x8 pw[3][3][2];
#pragma unroll
      for (int r = 0; r < 3; ++r)
#pragma unroll
        for (int g = 0; g < 3; ++g)
#pragma unroll
          for (int fn = 0; fn < 2; ++fn)
            pw[r][g][fn] = *(const bf16x8*)(Whh +
                (size_t)(g * 256 + wc * 32 + fn * 16 + (l & 15)) * 256 + r * 32 + (l >> 4) * 8);
#pragma unroll
      for (int kk = 0; kk < 8; ++kk) {
        int slot = kk % 3;
        bf16x8 av = *(const bf16x8*)(hB[dir] + (l & 15) * HLD + kk * 32 + (l >> 4) * 8);
#pragma unroll
        for (int g = 0; g < 3; ++g)
#pragma unroll
          for (int fn = 0; fn < 2; ++fn)
            ae[g][fn] = __builtin_amdgcn_mfma_f32_16x16x32_bf16(av, pw[slot][g][fn], ae[g][fn], 0, 0, 0);
        if (kk + 3 < 8) {
#pragma unroll
          for (int g = 0; g < 3; ++g)
#pragma unroll
            for (int fn = 0; fn < 2; ++fn)
              pw[slot][g][fn] = *(const bf16x8*)(Whh +
                  (size_t)(g * 256 + wc * 32 + fn * 16 + (l & 15)) * 256 + (kk + 3) * 32 + (l >> 4) * 8);
        }
      }
    }
    __syncthreads();
#pragma unroll
    for (int fn = 0; fn < 2; ++fn) {
      int c = wc * 32 + fn * 16 + (l & 15);
      float bR = bhh[c], bZ = bhh[256 + c], bN = bhh[512 + c];
#pragma unroll
      for (int j = 0; j < 4; ++j) {
        int row = (l >> 4) * 4 + j;
        if (row < 4) {
          const float* tb = tab + (size_t)toks[row * 32 + s_store] * 768 + c;
          float rg = sgm(tb[0] + ae[0][fn][j] + bR);
          float zg = sgm(tb[256] + ae[1][fn][j] + bZ);
          float ng = tanh_fast(tb[512] + rg * (ae[2][fn][j] + bN));
          float hold = hF[dir][row * HFLD + c];
          float hv = (1.f - zg) * ng + zg * hold;
          hF[dir][row * HFLD + c] = hv;
          u16 hb16 = f2b(hv);
          hB[dir][row * HLD + c] = hb16;
          __builtin_nontemporal_store(
              hb16, E.enc_b + ((size_t)(r0 + row) * SLEN + s_store) * 512 + dir * 256 + c);
        }
      }
    }
    __syncthreads();
  }
  for (int i = tid; i < 4 * 512; i += 1024) {
    int r = i >> 9, c = i & 511;
    E.hcatB[(size_t)(r0 + r) * 512 + c] =
        (c < 256) ? hB[0][r * HLD + c] : hB[1][r * HLD + (c - 256)];
  }
}

// ---------------- persistent decoder: 256 blocks x 4 rows, enc_b in LDS ----------
// Manual LDS layout (total ~145KB). MFMA A-fragments over-read rows 4-15 of hB/ctxB;
// those addresses land inside later LDS regions (ebL) — values unused (D rows 4-15
// are never read out), so this is safe by construction.
#define OFF_HB    0                     // 4 * HLD u16        = 2112 B
#define OFF_CTX   2112                  // 4 * CTXLD u16      = 4160 B
#define OFF_HF    6272                  // 4 * HFLD f32       = 4160 B
#define OFF_HW    10432                 // 4 * HWLD f32       = 4160 B
#define OFF_AW    14592                 // 4*33 f32           = 528 B
#define OFF_SC    15120                 // 4*32 f32           = 512 B
#define OFF_VS    15632                 // 256 f32            = 1024 B
#define OFF_TOK   16656                 // 128 int            = 512 B
#define OFF_EB    17168                 // 4*32*512 u16       = 131072 B
#define SMEM_TOT  148240

struct DecArgs {
  const u16* enc_b; const u16* enc_pre_b; const float* v_attn;
  const u16* Wd_b; const u16* Wg_lo; const u16* Wg_hi;
  const float* tabd; const float* dbhh;
  const int* trg; const float* h0f;
  u16* bcat;
};

__global__ __launch_bounds__(1024) void k_dec_p(DecArgs A) {
  __shared__ __align__(16) char smem[SMEM_TOT];
  u16* hB = (u16*)(smem + OFF_HB);
  u16* ctxB = (u16*)(smem + OFF_CTX);
  float* hF = (float*)(smem + OFF_HF);
  float* hwS = (float*)(smem + OFF_HW);
  float* awS = (float*)(smem + OFF_AW);
  float* scS = (float*)(smem + OFF_SC);
  float* vS = (float*)(smem + OFF_VS);
  int* toks = (int*)(smem + OFF_TOK);
  u16* ebL = (u16*)(smem + OFF_EB);
  int r0 = blockIdx.x * 4;
  int tid = threadIdx.x, w = tid >> 6, l = tid & 63;
  // stage enc_b slice (4 rows x 32 s x 512) into LDS, sp-XOR-swizzled chunks
  {
    const u16* src = A.enc_b + (size_t)r0 * SLEN * 512;
#pragma unroll
    for (int i = 0; i < 8; ++i) {
      int idx = (tid + i * 1024) * 8;           // u16 index, 16B chunks
      int srow = idx >> 9;                       // r*32 + s
      int chunk = (idx & 511) >> 3;              // 0..63
      int sp = (srow >> 3) & 3;
      bf16x8 v = *(const bf16x8*)(src + idx);
      *(bf16x8*)(ebL + srow * 512 + ((chunk ^ sp) << 3)) = v;
    }
  }
  {
    int r = tid >> 8, c = tid & 255;
    float v = A.h0f[(size_t)(r0 + r) * 256 + c];
    hF[r * HFLD + c] = v;
    hB[r * HLD + c] = f2b(v);
  }
  if (tid < 256) vS[tid] = A.v_attn[tid];
  if (tid < 128) toks[tid] = A.trg[(size_t)(r0 + (tid >> 5)) * TLEN + (tid & 31)];
  __syncthreads();
  for (int t = 0; t < TLEN - 1; ++t) {
    // ---- P1: hWd = h @ Wd^T : wave w -> cols [w*16, w*16+16), depth-4 ring ----
    {
      f32x4 a1 = {};
      bf16x8 pw[4];
#pragma unroll
      for (int r = 0; r < 4; ++r)
        pw[r] = *(const bf16x8*)(A.Wd_b + (size_t)(w * 16 + (l & 15)) * 256 + r * 32 + (l >> 4) * 8);
#pragma unroll
      for (int kk = 0; kk < 8; ++kk) {
        int slot = kk % 4;
        bf16x8 av = *(const bf16x8*)(hB + (l & 15) * HLD + kk * 32 + (l >> 4) * 8);
        a1 = __builtin_amdgcn_mfma_f32_16x16x32_bf16(av, pw[slot], a1, 0, 0, 0);
        if (kk + 4 < 8)
          pw[slot] = *(const bf16x8*)(A.Wd_b + (size_t)(w * 16 + (l & 15)) * 256 + (kk + 4) * 32 + (l >> 4) * 8);
      }
      int c = w * 16 + (l & 15);
#pragma unroll
      for (int j = 0; j < 4; ++j) {
        int row = (l >> 4) * 4 + j;
        if (row < 4) hwS[row * HWLD + c] = a1[j];
      }
    }
    __syncthreads();
    // ---- P2: scores: (r = tid>>8, s = (tid>>3)&31, part = tid&7) ----
    {
      int r = tid >> 8, s = (tid >> 3) & 31, part = tid & 7;
      const u16* ep = A.enc_pre_b + ((size_t)(r0 + r) * SLEN + s) * 256 + part * 32;
      const float* hw = hwS + r * HWLD + part * 32;
      const float* vv = vS + part * 32;
      float sum = 0.f;
#pragma unroll
      for (int a0 = 0; a0 < 32; a0 += 8) {
        bf16x8 pk = *(const bf16x8*)(ep + a0);
#pragma unroll
        for (int q = 0; q < 8; ++q)
          sum += vv[a0 + q] * tanh_fast(b2f((u16)pk[q]) + hw[a0 + q]);
      }
      sum += __shfl_xor(sum, 1);
      sum += __shfl_xor(sum, 2);
      sum += __shfl_xor(sum, 4);
      if (part == 0) scS[r * 32 + s] = sum;
    }
    __syncthreads();
    // softmax over s: tid<128, r = tid>>5, s = tid&31
    if (tid < 128) {
      int r = tid >> 5, s = tid & 31;
      float v = scS[r * 32 + s], m = v;
#pragma unroll
      for (int o = 1; o <= 16; o <<= 1) m = fmaxf(m, __shfl_xor(m, o));
      float e = __expf(v - m), ss = e;
#pragma unroll
      for (int o = 1; o <= 16; o <<= 1) ss += __shfl_xor(ss, o);
      awS[r * 33 + s] = e / ss;
    }
    __syncthreads();
    // ---- P3: ctx from ebL (LDS): (r = tid>>8, c8 = (tid>>2)&63, sp = tid&3) ----
    {
      int r = tid >> 8, ch = (tid >> 2) & 63, sp = tid & 3;
      int c = ch * 8;
      float a8[8] = {};
      const u16* eb = ebL + (r * 32 + sp * 8) * 512 + ((ch ^ sp) << 3);
#pragma unroll
      for (int s2 = 0; s2 < 8; ++s2) {
        float a = awS[r * 33 + sp * 8 + s2];
        bf16x8 pk = *(const bf16x8*)(eb + s2 * 512);
#pragma unroll
        for (int q = 0; q < 8; ++q) a8[q] += a * b2f((u16)pk[q]);
      }
#pragma unroll
      for (int o = 1; o <= 2; o <<= 1)
#pragma unroll
        for (int q = 0; q < 8; ++q) a8[q] += __shfl_xor(a8[q], o);
      if (sp == 0) {
        bf16x8 o;
#pragma unroll
        for (int q = 0; q < 8; ++q) o[q] = (short)f2b(a8[q]);
        *(bf16x8*)(ctxB + r * CTXLD + c) = o;
        __builtin_nontemporal_store(
            o, (bf16x8*)(A.bcat + ((size_t)t * BSZ + r0 + r) * 768 + 256 + c));
      }
    }
    __syncthreads();
    // ---- P4: gates, depth-6 register ring over 24 k-iters ----
    f32x4 ag[4] = {};
    {
      bf16x8 pf[6][3];
#pragma unroll
      for (int r = 0; r < 6; ++r)
#pragma unroll
        for (int gb = 0; gb < 3; ++gb)
          pf[r][gb] = *(const bf16x8*)(A.Wg_lo +
              (size_t)(gb * 256 + w * 16 + (l & 15)) * 512 + r * 32 + (l >> 4) * 8);
#pragma unroll
      for (int kk = 0; kk < 24; ++kk) {
        int slot = kk % 6;
        bf16x8 av = (kk < 16)
            ? *(const bf16x8*)(ctxB + (l & 15) * CTXLD + kk * 32 + (l >> 4) * 8)
            : *(const bf16x8*)(hB + (l & 15) * HLD + (kk - 16) * 32 + (l >> 4) * 8);
#pragma unroll
        for (int gb = 0; gb < 3; ++gb) {
          int ai = (kk < 16) ? gb : (gb == 2 ? 3 : gb);
          ag[ai] = __builtin_amdgcn_mfma_f32_16x16x32_bf16(av, pf[slot][gb], ag[ai], 0, 0, 0);
        }
        int kn = kk + 6;
        if (kn < 24) {
#pragma unroll
          for (int gb = 0; gb < 3; ++gb) {
            if (kn < 16)
              pf[slot][gb] = *(const bf16x8*)(A.Wg_lo +
                  (size_t)(gb * 256 + w * 16 + (l & 15)) * 512 + kn * 32 + (l >> 4) * 8);
            else
              pf[slot][gb] = *(const bf16x8*)(A.Wg_hi +
                  (size_t)(gb * 256 + w * 16 + (l & 15)) * 256 + (kn - 16) * 32 + (l >> 4) * 8);
          }
        }
      }
    }
    __syncthreads();
    // ---- P5: GRU epilogue: wave w -> col c = w*16 + (l&15), rows < 4 ----
    {
      int c = w * 16 + (l & 15);
      float bR = A.dbhh[c], bZ = A.dbhh[256 + c], bN = A.dbhh[512 + c];
#pragma unroll
      for (int j = 0; j < 4; ++j) {
        int row = (l >> 4) * 4 + j;
        if (row < 4) {
          const float* tb = A.tabd + (size_t)toks[row * 32 + t] * 768 + c;
          float rg = sgm(tb[0] + ag[0][j] + bR);
          float zg = sgm(tb[256] + ag[1][j] + bZ);
          float ng = tanh_fast(tb[512] + ag[2][j] + rg * (ag[3][j] + bN));
          float hold = hF[row * HFLD + c];
          float hv = (1.f - zg) * ng + zg * hold;
          hF[row * HFLD + c] = hv;
          u16 hb16 = f2b(hv);
          hB[row * HLD + c] = hb16;
          __builtin_nontemporal_store(hb16,
                                      A.bcat + ((size_t)t * BSZ + r0 + row) * 768 + c);
        }
      }
    }
    __syncthreads();
  }
}

// ---------------- zero t=0 slice -------------------------------------------------
__global__ __launch_bounds__(256) void k_zero0(float* __restrict__ outp) {
  outp[(size_t)blockIdx.x * (TLEN * 256) + threadIdx.x] = 0.f;
}

extern "C" void kernel_launch(void* const* d_in, const int* in_sizes, int n_in,
                              void* d_out, int out_size, void* d_ws, size_t ws_size,
                              hipStream_t stream) {
  (void)in_sizes; (void)n_in; (void)out_size; (void)ws_size;
  const int* src = (const int*)d_in[0];
  const int* trg = (const int*)d_in[1];
  const float* enc_emb = (const float*)d_in[2];
  const float* eWih_f = (const float*)d_in[3];
  const float* eWhh_f = (const float*)d_in[4];
  const float* ebih_f = (const float*)d_in[5];
  const float* ebhh_f = (const float*)d_in[6];
  const float* eWih_b = (const float*)d_in[7];
  const float* eWhh_b = (const float*)d_in[8];
  const float* ebih_b = (const float*)d_in[9];
  const float* ebhh_b = (const float*)d_in[10];
  const float* Wproj = (const float*)d_in[11];
  const float* bproj = (const float*)d_in[12];
  const float* dec_emb = (const float*)d_in[13];
  const float* Wattn = (const float*)d_in[14];
  const float* battn = (const float*)d_in[15];
  const float* v_attn = (const float*)d_in[16];
  const float* dWih = (const float*)d_in[17];
  const float* dWhh = (const float*)d_in[18];
  const float* dbih = (const float*)d_in[19];
  const float* dbhh = (const float*)d_in[20];
  const float* Wfc = (const float*)d_in[21];
  const float* bfc = (const float*)d_in[22];
  float* dout = (float*)d_out;

  char* base = (char*)d_ws;
  size_t off = 0;
  auto alloc = [&](size_t bytes) {
    void* p = base + off;
    off += (bytes + 255) & ~(size_t)255;
    return p;
  };
  u16* enc_b     = (u16*)alloc((size_t)BSZ * SLEN * 512 * 2);
  u16* enc_pre_b = (u16*)alloc((size_t)BSZ * SLEN * 256 * 2);
  u16* bcat      = (u16*)alloc((size_t)31 * BSZ * 768 * 2);
  float* tabf    = (float*)alloc((size_t)64 * 768 * 4);
  float* tabb    = (float*)alloc((size_t)64 * 768 * 4);
  float* tabd    = (float*)alloc((size_t)256 * 768 * 4);
  u16* hcatB     = (u16*)alloc((size_t)BSZ * 512 * 2);
  float* h0f     = (float*)alloc((size_t)BSZ * 256 * 4);
  u16* Whhf_b    = (u16*)alloc((size_t)768 * 256 * 2);
  u16* Whhb_b    = (u16*)alloc((size_t)768 * 256 * 2);
  u16* We_b      = (u16*)alloc((size_t)256 * 512 * 2);
  u16* Wd_b      = (u16*)alloc((size_t)256 * 256 * 2);
  u16* Wproj_b   = (u16*)alloc((size_t)256 * 512 * 2);
  u16* Wg_lo     = (u16*)alloc((size_t)768 * 512 * 2);
  u16* Wg_hi     = (u16*)alloc((size_t)768 * 256 * 2);
  u16* Wfc_b     = (u16*)alloc((size_t)256 * 768 * 2);

  // tables + weight packs
  k_gi_table<<<dim3(64, 3), 256, 0, stream>>>(enc_emb, eWih_f, EDIM, ebih_f, tabf);
  k_gi_table<<<dim3(64, 3), 256, 0, stream>>>(enc_emb, eWih_b, EDIM, ebih_b, tabb);
  k_gi_table<<<dim3(256, 3), 256, 0, stream>>>(dec_emb, dWih, 640, dbih, tabd);
  k_pack<<<dim3(768), 256, 0, stream>>>(Whhf_b, eWhh_f, 256, 0, 256);
  k_pack<<<dim3(768), 256, 0, stream>>>(Whhb_b, eWhh_b, 256, 0, 256);
  k_pack<<<dim3(256), 256, 0, stream>>>(We_b, Wattn, 768, 256, 512);
  k_pack<<<dim3(256), 256, 0, stream>>>(Wd_b, Wattn, 768, 0, 256);
  k_pack<<<dim3(256), 256, 0, stream>>>(Wproj_b, Wproj, 512, 0, 512);
  k_pack<<<dim3(768), 256, 0, stream>>>(Wg_lo, dWih, 640, 128, 512);
  k_pack<<<dim3(768), 256, 0, stream>>>(Wg_hi, dWhh, 256, 0, 256);
  k_pack<<<dim3(256), 256, 0, stream>>>(Wfc_b, Wfc, 768, 0, 768);

  // encoder: persistent, 256 blocks x 4 rows, zero grid sync
  {
    EncArgs ea{enc_b, hcatB, src, Whhf_b, Whhb_b, ebhh_f, ebhh_b, tabf, tabb};
    k_enc_p<<<dim3(256), dim3(1024), 0, stream>>>(ea);
  }

  // hdec = hcat @ Wproj^T + bproj (fp32 out)
  k_bgemm<false><<<dim3(8, 4), 256, 0, stream>>>(hcatB, 512, Wproj_b, 512, bproj, h0f, 256, 512);
  // enc_pre (bf16) = enc_b @ We^T + battn
  k_bgemm<true><<<dim3(256, 4), 256, 0, stream>>>(enc_b, 512, We_b, 512, battn,
                                                  enc_pre_b, 256, 512);
  k_zero0<<<dim3(BSZ), 256, 0, stream>>>(dout);

  // decoder: persistent, 256 blocks x 4 rows, enc_b staged in LDS
  {
    DecArgs da{enc_b, enc_pre_b, v_attn, Wd_b, Wg_lo, Wg_hi, tabd, dbhh, trg, h0f, bcat};
    k_dec_p<<<dim3(256), dim3(1024), 0, stream>>>(da);
  }

  // deferred logits: [hn|ctx] @ Wfc^T + bfc for all 31 steps at once
  k_bgemm_logits<<<dim3(248, 4), 256, 0, stream>>>(bcat, Wfc_b, bfc, dout);
}